// Round 12
// baseline (861.275 us; speedup 1.0000x reference)
//
#include <hip/hip_runtime.h>

// ---------------------------------------------------------------------------
// TeacherModel: small U-Net + pose heads. B=8, H=W=384, fp32 NCHW.
// Round 25: barrier-free heads. 1x1 conv A-fragments are directly loadable
//  from global (coalesced 16B per lane, same values/order as the LDS
//  round-trip) -> drop per-chunk staging + 8 barriers; LDS only for the
//  epilogue transpose (16 KB -> 10 blocks/CU). Bit-identical.
// R24: d2 4x48 exact-rounds. R23: u1 4x48 exact-rounds. R22: packw_all,
//  heads merge, pooled epilogues. R21: d1 conv+pool fusion.
// R18: split planes [C/8][H][W][8] (hi/lo), producer-side.
// Workspace lifetime map (floats, 56,623,104 total):
//  pd1sp h/l  [0..4.7M)+[4.7M..9.4M)        s1->s3
//  d2sp h/l   [28.3M..37.7M)+[37.7M..47.2M) s3->s6
//  pd2sp h/l  [47.2M..49.5M)+[49.5M..51.9M) s3->s5
//  bnsp h/l   [18.9M..23.6M)+[23.6M..28.3M) s5->s6
//  u1sp h/l   [0..9.4M)+[9.4M..18.9M)       s6->s8
//  d1sp h/l   [18.9M..37.7M)+[37.7M..56.6M) s7->s8
//  p1sp h/l   [0..9.4M)+[9.4M..18.9M)       s9->s10
//  p2sp h/l   [18.9M..23.6M)+[23.6M..28.3M) s10->s12
// ---------------------------------------------------------------------------

#define BS 256
#define BSW 512     // 8-wave blocks (u2seg)

typedef _Float16 half8 __attribute__((ext_vector_type(8)));
typedef float floatx4 __attribute__((ext_vector_type(4)));

#define LDSDW 20    // dwords per x position
#define PLT8 10000  // 10*50*LDSDW dwords per plane (8-row x 48-px kernels)
#define PLT4 6000   // 6*50*LDSDW dwords per plane (4-row x 48-px kernels)
#define ESTR 388    // 8-row epilogue buffer stride (dw)
#define ESTR4 196   // 4-row epilogue buffer stride (dw): 192+4

// ===========================================================================
// Weight pre-pack (device bodies + single merged kernel).
// ===========================================================================
__device__ inline void packw_gen_body(
    const float* __restrict__ w, _Float16* __restrict__ bp, int Cin, int Cout,
    int tid, int total)
{
    int lane = tid & 63;
    int t = tid >> 6;
    int NTl = Cout >> 4;
    int nt = t % NTl; t /= NTl;
    int tap = t % 9;
    int chunk = t / 9;
    int q = lane >> 4, n = lane & 15;
    int co = nt * 16 + n;
    _Float16* ph = bp + (size_t)tid * 8;
    _Float16* pl = bp + (size_t)total * 8 + (size_t)tid * 8;
#pragma unroll
    for (int j = 0; j < 8; ++j) {
        int ci = chunk * 32 + q * 8 + j;
        float v = w[((size_t)co * Cin + ci) * 9 + tap];
        _Float16 h = (_Float16)v;
        ph[j] = h;
        pl[j] = (_Float16)(v - (float)h);
    }
}

__device__ inline void packw_1x1_body(
    const float* __restrict__ w, _Float16* __restrict__ bp, int Cin, int NTl, int Cout,
    int tid, int total)
{
    int lane = tid & 63;
    int t = tid >> 6;
    int nt = t % NTl;
    int chunk = t / NTl;
    int q = lane >> 4, n = lane & 15;
    int co = nt * 16 + n;
    _Float16* ph = bp + (size_t)tid * 8;
    _Float16* pl = bp + (size_t)total * 8 + (size_t)tid * 8;
#pragma unroll
    for (int j = 0; j < 8; ++j) {
        int ci = chunk * 32 + q * 8 + j;
        float v = (co < Cout) ? w[(size_t)co * Cin + ci] : 0.f;
        _Float16 h = (_Float16)v;
        ph[j] = h;
        pl[j] = (_Float16)(v - (float)h);
    }
}

__global__ __launch_bounds__(BS) void packw_all_kernel(
    const float* __restrict__ w_u1, const float* __restrict__ w_u2,
    const float* __restrict__ w_d2, const float* __restrict__ w_bn,
    const float* __restrict__ w_p2, const float* __restrict__ w_hm,
    const float* __restrict__ w_paf,
    _Float16* __restrict__ bp_u1, _Float16* __restrict__ bp_u2,
    _Float16* __restrict__ bp_d2, _Float16* __restrict__ bp_bn,
    _Float16* __restrict__ bp_p2, _Float16* __restrict__ bp_hm,
    _Float16* __restrict__ bp_paf)
{
    int tid = blockIdx.x * BS + threadIdx.x;
    if (tid < 13824) { packw_gen_body(w_u1, bp_u1, 192, 64, tid, 13824); return; }
    tid -= 13824;
    if (tid < 3456)  { packw_gen_body(w_u2, bp_u2, 96, 32, tid, 3456); return; }
    tid -= 3456;
    if (tid < 2304)  { packw_gen_body(w_d2, bp_d2, 32, 64, tid, 2304); return; }
    tid -= 2304;
    if (tid < 9216)  { packw_gen_body(w_bn, bp_bn, 64, 128, tid, 9216); return; }
    tid -= 9216;
    if (tid < 9216)  { packw_gen_body(w_p2, bp_p2, 64, 128, tid, 9216); return; }
    tid -= 9216;
    if (tid < 512)   { packw_1x1_body(w_hm, bp_hm, 128, 2, 17, tid, 512); return; }
    tid -= 512;
    if (tid < 512)   { packw_1x1_body(w_paf, bp_paf, 128, 2, 32, tid, 512); return; }
}

// ===========================================================================
// d1 fused: conv3x3(x; 3->32) + relu + 2x2 maxpool -> pooled split planes. (R21)
// ===========================================================================
template <int TCO>
__global__ __launch_bounds__(BS, 2) void conv3x3_pool_kernel(
    const float* __restrict__ inA, int Ca,
    const float* __restrict__ w, const float* __restrict__ b,
    _Float16* __restrict__ oph, _Float16* __restrict__ opl,
    int N, int H, int W, int Cout)
{
    const int W8 = W >> 3;
    const int H2 = H >> 1, W2 = W >> 1;
    int idx = blockIdx.x * BS + threadIdx.x;
    int total = N * H2 * W8;
    if (idx >= total) return;
    int x8 = idx % W8;
    int t  = idx / W8;
    int yo = t % H2;
    int n  = t / H2;
    int x0 = x8 << 3;
    const int co0 = blockIdx.y * TCO;
    const bool left_ok  = (x0 > 0);
    const bool right_ok = (x0 + 8 < W);
    const int Cin = Ca;

    float pool[TCO][4];

#pragma unroll
    for (int rr = 0; rr < 2; ++rr) {
        int y = 2 * yo + rr;
        float acc[TCO][8];
#pragma unroll
        for (int j = 0; j < TCO; ++j) {
            float bv = b[co0 + j];
#pragma unroll
            for (int p = 0; p < 8; ++p) acc[j][p] = bv;
        }

        for (int ci = 0; ci < Cin; ++ci) {
            float v[3][10];
#pragma unroll
            for (int ky = 0; ky < 3; ++ky) {
                int iy = y + ky - 1;
                if (iy < 0 || iy >= H) {
#pragma unroll
                    for (int p = 0; p < 10; ++p) v[ky][p] = 0.f;
                    continue;
                }
                const float* r = inA + ((size_t)(n * Ca + ci) * H + iy) * W;
                v[ky][0] = left_ok ? r[x0 - 1] : 0.f;
                float4 q0 = *(const float4*)(r + x0);
                float4 q1 = *(const float4*)(r + x0 + 4);
                v[ky][1] = q0.x; v[ky][2] = q0.y; v[ky][3] = q0.z; v[ky][4] = q0.w;
                v[ky][5] = q1.x; v[ky][6] = q1.y; v[ky][7] = q1.z; v[ky][8] = q1.w;
                v[ky][9] = right_ok ? r[x0 + 8] : 0.f;
            }
#pragma unroll
            for (int j = 0; j < TCO; ++j) {
                const float* wp = w + ((size_t)(co0 + j) * Cin + ci) * 9;
#pragma unroll
                for (int ky = 0; ky < 3; ++ky) {
                    float w0 = wp[ky * 3 + 0], w1 = wp[ky * 3 + 1], w2 = wp[ky * 3 + 2];
#pragma unroll
                    for (int p = 0; p < 8; ++p)
                        acc[j][p] += w0 * v[ky][p] + w1 * v[ky][p + 1] + w2 * v[ky][p + 2];
                }
            }
        }

#pragma unroll
        for (int j = 0; j < TCO; ++j) {
#pragma unroll
            for (int p4 = 0; p4 < 4; ++p4) {
                float mrow = fmaxf(fmaxf(acc[j][2 * p4], 0.f),
                                   fmaxf(acc[j][2 * p4 + 1], 0.f));
                pool[j][p4] = (rr == 0) ? mrow : fmaxf(pool[j][p4], mrow);
            }
        }
    }

#pragma unroll
    for (int p4 = 0; p4 < 4; ++p4) {
        half8 hv, lv;
#pragma unroll
        for (int j = 0; j < 8; ++j) {
            float v = pool[j][p4];
            _Float16 h = (_Float16)v;
            hv[j] = h;
            lv[j] = (_Float16)(v - (float)h);
        }
        size_t oa = ((size_t)((n * (Cout >> 3) + (co0 >> 3)) * H2 + yo) * W2
                     + (x0 >> 1) + p4) * 8;
        *(half8*)(oph + oa) = hv;
        *(half8*)(opl + oa) = lv;
    }
}

// ===========================================================================
// Generic stride-1 3x3 SAME conv via MFMA, SPLIT input: block = 2 rows x 32 px.
// OUTMODE: 1 = split only (bn).
// ===========================================================================
template <int CHUNKS, int NT, int HH, int WW, int OUTMODE>
__global__ __launch_bounds__(BS) void conv3x3s_mfma_kernel(
    const _Float16* __restrict__ inh, const _Float16* __restrict__ inl,
    const _Float16* __restrict__ bp,
    const float* __restrict__ bias,
    _Float16* __restrict__ osph,
    _Float16* __restrict__ ospl)
{
    constexpr int PL = 4 * 34 * LDSDW;
    constexpr int EPI = 64 * NT * 16;
    constexpr int LDS_DW = (2 * PL > EPI) ? 2 * PL : EPI;
    __shared__ unsigned int lds[LDS_DW];

    int xblks = WW / 32;
    int b = blockIdx.x;
    int xb = b % xblks; b /= xblks;
    int yp = b % (HH / 2);
    int n  = b / (HH / 2);
    int y0 = yp * 2;
    int x0 = xb * 32;

    int tid = threadIdx.x;
    int lane = tid & 63, wv = tid >> 6;
    int m = lane & 15, q = lane >> 4;
    int lrow = wv >> 1;
    int lx   = (wv & 1) * 16;

    floatx4 acc[NT];
#pragma unroll
    for (int nt = 0; nt < NT; ++nt) acc[nt] = (floatx4){0.f, 0.f, 0.f, 0.f};

    const int planeW = CHUNKS * 9 * NT * 64 * 8;

    for (int chunk = 0; chunk < CHUNKS; ++chunk) {
        __syncthreads();
        for (int e = tid; e < 4 * 34 * 4; e += BS) {
            int xi = e % 34;
            int rest = e / 34;
            int oct = rest & 3;
            int row = rest >> 2;
            int iy = y0 - 1 + row, gx = x0 - 1 + xi;
            half8 hv = {}, lv = {};
            if (iy >= 0 && iy < HH && gx >= 0 && gx < WW) {
                size_t ga = ((size_t)((n * (CHUNKS * 4) + chunk * 4 + oct) * HH + iy) * WW + gx) * 8;
                hv = *(const half8*)(inh + ga);
                lv = *(const half8*)(inl + ga);
            }
            int base = (row * 34 + xi) * LDSDW + oct * 4;
            *(half8*)((char*)lds + (size_t)base * 4) = hv;
            *(half8*)((char*)lds + ((size_t)PL + base) * 4) = lv;
        }
        __syncthreads();
#pragma unroll
        for (int ky = 0; ky < 3; ++ky) {
#pragma unroll
            for (int kx = 0; kx < 3; ++kx) {
                int row = lrow + ky;
                int xi  = lx + m + kx;
                int adw = (row * 34 + xi) * LDSDW + q * 4;
                half8 ah = *(const half8*)((const char*)lds + (size_t)adw * 4);
                half8 al = *(const half8*)((const char*)lds + ((size_t)PL + adw) * 4);
                int tap = ky * 3 + kx;
                const _Float16* bpp = bp + ((size_t)(chunk * 9 + tap) * NT) * 64 * 8;
#pragma unroll
                for (int nt = 0; nt < NT; ++nt) {
                    half8 bh = *(const half8*)(bpp + ((size_t)nt * 64 + lane) * 8);
                    half8 bl = *(const half8*)(bpp + planeW + ((size_t)nt * 64 + lane) * 8);
                    acc[nt] = __builtin_amdgcn_mfma_f32_16x16x32_f16(ah, bh, acc[nt], 0, 0, 0);
                    acc[nt] = __builtin_amdgcn_mfma_f32_16x16x32_f16(ah, bl, acc[nt], 0, 0, 0);
                    acc[nt] = __builtin_amdgcn_mfma_f32_16x16x32_f16(al, bh, acc[nt], 0, 0, 0);
                }
            }
        }
    }

    __syncthreads();
#pragma unroll
    for (int nt = 0; nt < NT; ++nt) {
#pragma unroll
        for (int r = 0; r < 4; ++r) {
            int co = nt * 16 + m;
            int pxl = wv * 16 + q * 4 + r;
            ((float*)lds)[co * 64 + pxl] = acc[nt][r];
        }
    }
    __syncthreads();
    {
        constexpr int OCTS = NT * 2;
        for (int it = tid; it < OCTS * 64; it += BS) {
            int px = it & 63;
            int oct = it >> 6;
            int row = y0 + (px >> 5), xx = x0 + (px & 31);
            half8 hv, lv;
#pragma unroll
            for (int j = 0; j < 8; ++j) {
                float v = fmaxf(((float*)lds)[(oct * 8 + j) * 64 + px] + bias[oct * 8 + j], 0.f);
                _Float16 hh = (_Float16)v;
                hv[j] = hh;
                lv[j] = (_Float16)(v - (float)hh);
            }
            size_t oaddr = ((size_t)((n * OCTS + oct) * HH + row) * WW + xx) * 8;
            *(half8*)(osph + oaddr) = hv;
            *(half8*)(ospl + oaddr) = lv;
        }
    }
}

// ===========================================================================
// d2 = relu(conv3x3(pd1; 32->64)) @192, 4 rows x 48 px (R24: exact rounds).
// ===========================================================================
__global__ __launch_bounds__(BS) void d2_mfma4_kernel(
    const _Float16* __restrict__ inh, const _Float16* __restrict__ inl,  // pd1sp [8,4,192,192,8]
    const _Float16* __restrict__ bp,                                     // bp_d2 (9 taps x 4nt)
    const float* __restrict__ bias,                                      // b_d2 [64]
    _Float16* __restrict__ oh, _Float16* __restrict__ ol_,               // d2sp [8,8,192,192,8]
    _Float16* __restrict__ oph, _Float16* __restrict__ opl)              // pd2sp [8,8,96,96,8]
{
    __shared__ unsigned int lds[2 * PLT4 + 128];
    const int Ho = 192, Wo = 192;
    int b = blockIdx.x;
    int xb = b % 4; b /= 4;
    int yb = b % 48;
    int n  = b / 48;
    int y0 = yb * 4;
    int x0 = xb * 48;

    int tid = threadIdx.x;
    int lane = tid & 63, wv = tid >> 6;               // wv 0..3
    int m = lane & 15, q = lane >> 4;

    floatx4 acc[3][4];
#pragma unroll
    for (int mt = 0; mt < 3; ++mt)
#pragma unroll
        for (int nt = 0; nt < 4; ++nt) acc[mt][nt] = (floatx4){0.f, 0.f, 0.f, 0.f};

    for (int e = tid; e < 6 * 50 * 4; e += BS) {
        int xi = e % 50;
        int rest = e / 50;
        int oct = rest & 3;
        int row = rest >> 2;
        int iy = y0 - 1 + row, gx = x0 - 1 + xi;
        half8 hv = {}, lv = {};
        if (iy >= 0 && iy < Ho && gx >= 0 && gx < Wo) {
            size_t ga = ((size_t)((n * 4 + oct) * Ho + iy) * Wo + gx) * 8;
            hv = *(const half8*)(inh + ga);
            lv = *(const half8*)(inl + ga);
        }
        int base = (row * 50 + xi) * LDSDW + oct * 4;
        *(half8*)((char*)lds + (size_t)base * 4) = hv;
        *(half8*)((char*)lds + ((size_t)PLT4 + base) * 4) = lv;
    }
    __syncthreads();
#pragma unroll
    for (int ky = 0; ky < 3; ++ky) {
#pragma unroll
        for (int kx = 0; kx < 3; ++kx) {
            int tap = ky * 3 + kx;
            const _Float16* bpp = bp + (size_t)tap * 2048;
            half8 bh[4], bl[4];
#pragma unroll
            for (int nt = 0; nt < 4; ++nt) {
                bh[nt] = *(const half8*)(bpp + ((size_t)nt * 64 + lane) * 8);
                bl[nt] = *(const half8*)(bpp + 18432 + ((size_t)nt * 64 + lane) * 8);
            }
            int row = wv + ky;
#pragma unroll
            for (int mt = 0; mt < 3; ++mt) {
                int px = 16 * mt + m;
                int xi = px + kx;
                int adw = (row * 50 + xi) * LDSDW + q * 4;
                half8 ah = *(const half8*)((const char*)lds + (size_t)adw * 4);
                half8 al = *(const half8*)((const char*)lds + ((size_t)PLT4 + adw) * 4);
#pragma unroll
                for (int nt = 0; nt < 4; ++nt) {
                    acc[mt][nt] = __builtin_amdgcn_mfma_f32_16x16x32_f16(ah, bh[nt], acc[mt][nt], 0, 0, 0);
                    acc[mt][nt] = __builtin_amdgcn_mfma_f32_16x16x32_f16(ah, bl[nt], acc[mt][nt], 0, 0, 0);
                    acc[mt][nt] = __builtin_amdgcn_mfma_f32_16x16x32_f16(al, bh[nt], acc[mt][nt], 0, 0, 0);
                }
            }
        }
    }

#pragma unroll
    for (int h = 0; h < 2; ++h) {
        __syncthreads();
#pragma unroll
        for (int ntl = 0; ntl < 2; ++ntl) {
#pragma unroll
            for (int mt = 0; mt < 3; ++mt) {
#pragma unroll
                for (int r = 0; r < 4; ++r) {
                    ((float*)lds)[(ntl * 16 + m) * ESTR4 + wv * 48 + 16 * mt + q * 4 + r]
                        = acc[mt][h * 2 + ntl][r];
                }
            }
        }
        __syncthreads();
        for (int it = tid; it < 4 * 192; it += BS) {
            int px = it % 192;
            int ol = it / 192;
            int row = y0 + px / 48, xx = x0 + px % 48;
            half8 hv, lv;
#pragma unroll
            for (int j = 0; j < 8; ++j) {
                int col = ol * 8 + j;
                float v = fmaxf(((float*)lds)[col * ESTR4 + px] + bias[h * 32 + col], 0.f);
                _Float16 hh = (_Float16)v;
                hv[j] = hh;
                lv[j] = (_Float16)(v - (float)hh);
            }
            size_t oaddr = ((size_t)((n * 8 + h * 4 + ol) * Ho + row) * Wo + xx) * 8;
            *(half8*)(oh + oaddr) = hv;
            *(half8*)(ol_ + oaddr) = lv;
        }
        for (int it = tid; it < 4 * 2 * 24; it += BS) {
            int xo = it % 24;
            int rest = it / 24;
            int ro = rest & 1;
            int ol = rest >> 1;
            half8 hv, lv;
#pragma unroll
            for (int j = 0; j < 8; ++j) {
                int col = ol * 8 + j;
                float bb = bias[h * 32 + col];
                const float* buf = (const float*)lds + col * ESTR4;
                float t0 = fmaxf(fmaxf(buf[(2 * ro) * 48 + 2 * xo] + bb, 0.f),
                                 fmaxf(buf[(2 * ro) * 48 + 2 * xo + 1] + bb, 0.f));
                float t1 = fmaxf(fmaxf(buf[(2 * ro + 1) * 48 + 2 * xo] + bb, 0.f),
                                 fmaxf(buf[(2 * ro + 1) * 48 + 2 * xo + 1] + bb, 0.f));
                float v = fmaxf(t0, t1);
                _Float16 hh = (_Float16)v;
                hv[j] = hh;
                lv[j] = (_Float16)(v - (float)hh);
            }
            size_t oaddr = ((size_t)((n * 8 + h * 4 + ol) * 96 + (yb * 2 + ro)) * 96
                            + (xb * 24 + xo)) * 8;
            *(half8*)(oph + oaddr) = hv;
            *(half8*)(opl + oaddr) = lv;
        }
    }
}

// ===========================================================================
// Stride-2 3x3 conv via MFMA, SPLIT input + SPLIT output (p2).
// ===========================================================================
template <int CHUNKS, int NT, int WI>
__global__ __launch_bounds__(BS) void conv3x3s2s_mfma_kernel(
    const _Float16* __restrict__ inh, const _Float16* __restrict__ inl,
    const _Float16* __restrict__ bp,
    const float* __restrict__ bias,  // [NT*16]
    _Float16* __restrict__ oh, _Float16* __restrict__ ol_)  // [8, NT*2, WO, WO, 8]
{
    constexpr int WO = WI / 2;
    constexpr int PLs = 5 * 68 * LDSDW;
    constexpr int EPI = 64 * NT * 16;
    constexpr int LDS_DW = (2 * PLs > EPI) ? 2 * PLs : EPI;
    __shared__ unsigned int lds[LDS_DW];

    int xblks = WO / 32;
    int b = blockIdx.x;
    int xb = b % xblks; b /= xblks;
    int yp = b % (WO / 2);
    int n  = b / (WO / 2);
    int y0 = yp * 2;
    int x0 = xb * 32;

    int tid = threadIdx.x;
    int lane = tid & 63, wv = tid >> 6;
    int m = lane & 15, q = lane >> 4;
    int lrow = wv >> 1;
    int lx   = (wv & 1) * 16;

    floatx4 acc[NT];
#pragma unroll
    for (int nt = 0; nt < NT; ++nt) acc[nt] = (floatx4){0.f, 0.f, 0.f, 0.f};

    const int planeW = CHUNKS * 9 * NT * 64 * 8;

    for (int chunk = 0; chunk < CHUNKS; ++chunk) {
        __syncthreads();
        for (int e = tid; e < 5 * 68 * 4; e += BS) {
            int xi = e % 68;
            int rest = e / 68;
            int oct = rest & 3;
            int row = rest >> 2;
            int iy = 2 * y0 + row, ix = 2 * x0 + xi;
            half8 hv = {}, lv = {};
            if (xi < 65 && iy < WI && ix < WI) {
                size_t ga = ((size_t)((n * (CHUNKS * 4) + chunk * 4 + oct) * WI + iy) * WI + ix) * 8;
                hv = *(const half8*)(inh + ga);
                lv = *(const half8*)(inl + ga);
            }
            int pos = (xi & 1) * 34 + (xi >> 1);
            int base = (row * 68 + pos) * LDSDW + oct * 4;
            *(half8*)((char*)lds + (size_t)base * 4) = hv;
            *(half8*)((char*)lds + ((size_t)PLs + base) * 4) = lv;
        }
        __syncthreads();
#pragma unroll
        for (int ky = 0; ky < 3; ++ky) {
#pragma unroll
            for (int kx = 0; kx < 3; ++kx) {
                int row = 2 * lrow + ky;
                int pos = (kx & 1) * 34 + (lx + m) + (kx >> 1);
                int adw = (row * 68 + pos) * LDSDW + q * 4;
                half8 ah = *(const half8*)((const char*)lds + (size_t)adw * 4);
                half8 al = *(const half8*)((const char*)lds + ((size_t)PLs + adw) * 4);
                int tap = ky * 3 + kx;
                const _Float16* bpp = bp + ((size_t)(chunk * 9 + tap) * NT) * 64 * 8;
#pragma unroll
                for (int nt = 0; nt < NT; ++nt) {
                    half8 bh = *(const half8*)(bpp + ((size_t)nt * 64 + lane) * 8);
                    half8 bl = *(const half8*)(bpp + planeW + ((size_t)nt * 64 + lane) * 8);
                    acc[nt] = __builtin_amdgcn_mfma_f32_16x16x32_f16(ah, bh, acc[nt], 0, 0, 0);
                    acc[nt] = __builtin_amdgcn_mfma_f32_16x16x32_f16(ah, bl, acc[nt], 0, 0, 0);
                    acc[nt] = __builtin_amdgcn_mfma_f32_16x16x32_f16(al, bh, acc[nt], 0, 0, 0);
                }
            }
        }
    }

    __syncthreads();
#pragma unroll
    for (int nt = 0; nt < NT; ++nt) {
#pragma unroll
        for (int r = 0; r < 4; ++r) {
            int co = nt * 16 + m;
            int pxl = wv * 16 + q * 4 + r;
            ((float*)lds)[co * 64 + pxl] = acc[nt][r];
        }
    }
    __syncthreads();
    {
        constexpr int OCTS = NT * 2;
        for (int it = tid; it < OCTS * 64; it += BS) {
            int px = it & 63;
            int oct = it >> 6;
            int row = y0 + (px >> 5), xx = x0 + (px & 31);
            half8 hv, lv;
#pragma unroll
            for (int j = 0; j < 8; ++j) {
                float v = fmaxf(((float*)lds)[(oct * 8 + j) * 64 + px] + bias[oct * 8 + j], 0.f);
                _Float16 hh = (_Float16)v;
                hv[j] = hh;
                lv[j] = (_Float16)(v - (float)hh);
            }
            size_t oaddr = ((size_t)((n * OCTS + oct) * WO + row) * WO + xx) * 8;
            *(half8*)(oh + oaddr) = hv;
            *(half8*)(ol_ + oaddr) = lv;
        }
    }
}

// ===========================================================================
// Merged heads: hm (17) + paf (32) 1x1 convs over p2sp. R25: barrier-free —
// A-fragments read directly from global (coalesced 16B/lane, same values and
// order as the former LDS round-trip); LDS used only for the epilogue
// transpose (one barrier). Bit-identical.
// ===========================================================================
__global__ __launch_bounds__(BS) void conv1x1_heads_kernel(
    const _Float16* __restrict__ inh, const _Float16* __restrict__ inl,  // [8,16,HW,8]
    const _Float16* __restrict__ bph, const _Float16* __restrict__ bpp,  // bp_hm, bp_paf
    const float* __restrict__ bh_, const float* __restrict__ bpf,        // b_hm, b_paf
    float* __restrict__ out_hm, float* __restrict__ out_paf, int HW)
{
    __shared__ unsigned int lds[64 * 64];             // epilogue transpose only

    int pblks = HW / 64;
    int b = blockIdx.x;
    int pb = b % pblks;
    int n  = b / pblks;
    int sp0 = pb * 64;

    int tid = threadIdx.x;
    int lane = tid & 63, wv = tid >> 6;
    int m = lane & 15, q = lane >> 4;

    floatx4 acc[4];
#pragma unroll
    for (int nt = 0; nt < 4; ++nt) acc[nt] = (floatx4){0.f, 0.f, 0.f, 0.f};

    for (int chunk = 0; chunk < 4; ++chunk) {
        // direct-global A-fragment: px = wv*16+m, ci-octet = q (same values
        // the LDS staging delivered: lds[px][oct=q] <- inh[(.. + oct)*HW + px])
        size_t ga = (((size_t)(n * 16 + chunk * 4 + q)) * HW + sp0 + wv * 16 + m) * 8;
        half8 ah = *(const half8*)(inh + ga);
        half8 al = *(const half8*)(inl + ga);
#pragma unroll
        for (int nt = 0; nt < 4; ++nt) {
            const _Float16* base = (nt < 2) ? bph : bpp;
            int ntl = nt & 1;
            const _Float16* pbh = base + (size_t)(chunk * 2 + ntl) * 512 + (size_t)lane * 8;
            half8 bh = *(const half8*)pbh;
            half8 bl = *(const half8*)(pbh + 4096);
            acc[nt] = __builtin_amdgcn_mfma_f32_16x16x32_f16(ah, bh, acc[nt], 0, 0, 0);
            acc[nt] = __builtin_amdgcn_mfma_f32_16x16x32_f16(ah, bl, acc[nt], 0, 0, 0);
            acc[nt] = __builtin_amdgcn_mfma_f32_16x16x32_f16(al, bh, acc[nt], 0, 0, 0);
        }
    }

#pragma unroll
    for (int nt = 0; nt < 4; ++nt) {
#pragma unroll
        for (int r = 0; r < 4; ++r) {
            ((float*)lds)[(nt * 16 + m) * 64 + wv * 16 + q * 4 + r] = acc[nt][r];
        }
    }
    __syncthreads();
    {
        int co = tid >> 2;
        int g  = tid & 3;
        const float* lp = (const float*)lds + co * 64 + g * 16;
        if (co < 17) {
            float bb = bh_[co];
            float* op = out_hm + ((size_t)(n * 17 + co)) * HW + sp0 + g * 16;
#pragma unroll
            for (int u = 0; u < 16; u += 4) {
                float4 vv = *(const float4*)(lp + u);
                vv.x += bb; vv.y += bb; vv.z += bb; vv.w += bb;
                *(float4*)(op + u) = vv;
            }
        } else if (co >= 32) {
            int pco = co - 32;
            float bb = bpf[pco];
            float* op = out_paf + ((size_t)(n * 32 + pco)) * HW + sp0 + g * 16;
#pragma unroll
            for (int u = 0; u < 16; u += 4) {
                float4 vv = *(const float4*)(lp + u);
                vv.x += bb; vv.y += bb; vv.z += bb; vv.w += bb;
                *(float4*)(op + u) = vv;
            }
        }
    }
}

// ===========================================================================
// u1 = relu(conv3x3(concat(up2(bn), d2))) via MFMA, 4 rows x 48 px @192. (R23)
// ===========================================================================
__global__ __launch_bounds__(BS) void u1_mfma_kernel(
    const _Float16* __restrict__ bnh, const _Float16* __restrict__ bnl,  // [8,16,96,96,8]
    const _Float16* __restrict__ d2h, const _Float16* __restrict__ d2l,  // [8,8,192,192,8]
    const _Float16* __restrict__ bp,
    const float* __restrict__ b_u1,  // [64]
    _Float16* __restrict__ oh, _Float16* __restrict__ ol_)               // [8,8,192,192,8]
{
    __shared__ unsigned int lds[2 * PLT4 + 128];
    const int Ho = 192, Wo = 192;
    int b = blockIdx.x;
    int xb = b % 4; b /= 4;
    int yb = b % 48;
    int n  = b / 48;
    int y0 = yb * 4;
    int x0 = xb * 48;

    int tid = threadIdx.x;
    int lane = tid & 63, wv = tid >> 6;               // wv 0..3
    int m = lane & 15, q = lane >> 4;
    int yr = y0 + wv;

    floatx4 acc[3][4];
#pragma unroll
    for (int mt = 0; mt < 3; ++mt)
#pragma unroll
        for (int nt = 0; nt < 4; ++nt) acc[mt][nt] = (floatx4){0.f, 0.f, 0.f, 0.f};

    const int hh0 = (y0 - 1) >> 1;
    const int hx0 = (x0 - 1) >> 1;

    for (int chunk = 0; chunk < 6; ++chunk) {
        __syncthreads();
        if (chunk < 4) {
            for (int e = tid; e < 4 * 26 * 4; e += BS) {
                int xi = e % 26;
                int rest = e / 26;
                int oct = rest & 3;
                int row = rest >> 2;
                int hy = hh0 + row, hx = hx0 + xi;
                half8 hv = {}, lv = {};
                if (hy >= 0 && hy < 96 && hx >= 0 && hx < 96) {
                    size_t ga = ((size_t)((n * 16 + chunk * 4 + oct) * 96 + hy) * 96 + hx) * 8;
                    hv = *(const half8*)(bnh + ga);
                    lv = *(const half8*)(bnl + ga);
                }
                int base = (row * 50 + xi) * LDSDW + oct * 4;
                *(half8*)((char*)lds + (size_t)base * 4) = hv;
                *(half8*)((char*)lds + ((size_t)PLT4 + base) * 4) = lv;
            }
        } else {
            for (int e = tid; e < 6 * 50 * 4; e += BS) {
                int xi = e % 50;
                int rest = e / 50;
                int oct = rest & 3;
                int row = rest >> 2;
                int iy = y0 - 1 + row, gx = x0 - 1 + xi;
                half8 hv = {}, lv = {};
                if (iy >= 0 && iy < Ho && gx >= 0 && gx < Wo) {
                    size_t ga = ((size_t)((n * 8 + (chunk - 4) * 4 + oct) * Ho + iy) * Wo + gx) * 8;
                    hv = *(const half8*)(d2h + ga);
                    lv = *(const half8*)(d2l + ga);
                }
                int base = (row * 50 + xi) * LDSDW + oct * 4;
                *(half8*)((char*)lds + (size_t)base * 4) = hv;
                *(half8*)((char*)lds + ((size_t)PLT4 + base) * 4) = lv;
            }
        }
        __syncthreads();
#pragma unroll
        for (int ky = 0; ky < 3; ++ky) {
#pragma unroll
            for (int kx = 0; kx < 3; ++kx) {
                int tap = ky * 3 + kx;
                const _Float16* bpp = bp + ((size_t)(chunk * 9 + tap) * 4) * 64 * 8;
                half8 bh[4], bl[4];
#pragma unroll
                for (int nt = 0; nt < 4; ++nt) {
                    bh[nt] = *(const half8*)(bpp + ((size_t)nt * 64 + lane) * 8);
                    bl[nt] = *(const half8*)(bpp + 110592 + ((size_t)nt * 64 + lane) * 8);
                }
                int row;
                if (chunk < 4) row = ((yr + ky - 1) >> 1) - hh0;
                else           row = wv + ky;
#pragma unroll
                for (int mt = 0; mt < 3; ++mt) {
                    int px = 16 * mt + m;
                    int xi = (chunk < 4) ? (((x0 + px + kx - 1) >> 1) - hx0)
                                         : (px + kx);
                    int adw = (row * 50 + xi) * LDSDW + q * 4;
                    half8 ah = *(const half8*)((const char*)lds + (size_t)adw * 4);
                    half8 al = *(const half8*)((const char*)lds + ((size_t)PLT4 + adw) * 4);
#pragma unroll
                    for (int nt = 0; nt < 4; ++nt) {
                        acc[mt][nt] = __builtin_amdgcn_mfma_f32_16x16x32_f16(ah, bh[nt], acc[mt][nt], 0, 0, 0);
                        acc[mt][nt] = __builtin_amdgcn_mfma_f32_16x16x32_f16(ah, bl[nt], acc[mt][nt], 0, 0, 0);
                        acc[mt][nt] = __builtin_amdgcn_mfma_f32_16x16x32_f16(al, bh[nt], acc[mt][nt], 0, 0, 0);
                    }
                }
            }
        }
    }

    // epilogue: 2 halves of 32 co; buffer [32 co][stride ESTR4; 192 px used]
#pragma unroll
    for (int h = 0; h < 2; ++h) {
        __syncthreads();
#pragma unroll
        for (int ntl = 0; ntl < 2; ++ntl) {
#pragma unroll
            for (int mt = 0; mt < 3; ++mt) {
#pragma unroll
                for (int r = 0; r < 4; ++r) {
                    ((float*)lds)[(ntl * 16 + m) * ESTR4 + wv * 48 + 16 * mt + q * 4 + r]
                        = acc[mt][h * 2 + ntl][r];
                }
            }
        }
        __syncthreads();
        for (int it = tid; it < 4 * 192; it += BS) {
            int px = it % 192;
            int ol = it / 192;
            int row = y0 + px / 48, xx = x0 + px % 48;
            half8 hv, lv;
#pragma unroll
            for (int j = 0; j < 8; ++j) {
                int col = ol * 8 + j;
                float v = fmaxf(((float*)lds)[col * ESTR4 + px] + b_u1[h * 32 + col], 0.f);
                _Float16 hh = (_Float16)v;
                hv[j] = hh;
                lv[j] = (_Float16)(v - (float)hh);
            }
            size_t oaddr = ((size_t)((n * 8 + h * 4 + ol) * Ho + row) * Wo + xx) * 8;
            *(half8*)(oh + oaddr) = hv;
            *(half8*)(ol_ + oaddr) = lv;
        }
    }
}

// ===========================================================================
// seg via fused MFMA u2+seg, 8 rows x 48 px @384; shfl_xor co-reduce. (R18)
// ===========================================================================
__global__ __launch_bounds__(BSW) void u2seg_mfma_kernel(
    const _Float16* __restrict__ u1h, const _Float16* __restrict__ u1l,  // [8,8,192,192,8]
    const _Float16* __restrict__ d1h, const _Float16* __restrict__ d1l,  // [8,4,384,384,8]
    const _Float16* __restrict__ bp,
    const float* __restrict__ b_u2,  // [32]
    const float* __restrict__ w_seg, // [32]
    const float* __restrict__ b_seg, // [1]
    float* __restrict__ seg)         // [8,1,384,384]
{
    __shared__ unsigned int lds[2 * PLT8];
    const int Ho = 384, Wo = 384;
    int b = blockIdx.x;
    int xb = b % 8; b /= 8;
    int yb = b % 48;
    int n  = b / 48;
    int y0 = yb * 8;
    int x0 = xb * 48;

    int tid = threadIdx.x;
    int lane = tid & 63, wv = tid >> 6;
    int m = lane & 15, q = lane >> 4;
    int yr = y0 + wv;

    floatx4 acc[3][2];
#pragma unroll
    for (int mt = 0; mt < 3; ++mt) {
        acc[mt][0] = (floatx4){0.f, 0.f, 0.f, 0.f};
        acc[mt][1] = (floatx4){0.f, 0.f, 0.f, 0.f};
    }

    const int hh0 = (y0 - 1) >> 1;
    const int hx0 = (x0 - 1) >> 1;

    for (int chunk = 0; chunk < 3; ++chunk) {
        __syncthreads();
        if (chunk < 2) {
            for (int e = tid; e < 6 * 26 * 4; e += BSW) {
                int xi = e % 26;
                int rest = e / 26;
                int oct = rest & 3;
                int row = rest >> 2;
                int hy = hh0 + row, hx = hx0 + xi;
                half8 hv = {}, lv = {};
                if (hy >= 0 && hy < 192 && hx >= 0 && hx < 192) {
                    size_t ga = ((size_t)((n * 8 + chunk * 4 + oct) * 192 + hy) * 192 + hx) * 8;
                    hv = *(const half8*)(u1h + ga);
                    lv = *(const half8*)(u1l + ga);
                }
                int base = (row * 50 + xi) * LDSDW + oct * 4;
                *(half8*)((char*)lds + (size_t)base * 4) = hv;
                *(half8*)((char*)lds + ((size_t)PLT8 + base) * 4) = lv;
            }
        } else {
            for (int e = tid; e < 10 * 50 * 4; e += BSW) {
                int xi = e % 50;
                int rest = e / 50;
                int oct = rest & 3;
                int row = rest >> 2;
                int iy = y0 - 1 + row, gx = x0 - 1 + xi;
                half8 hv = {}, lv = {};
                if (iy >= 0 && iy < Ho && gx >= 0 && gx < Wo) {
                    size_t ga = ((size_t)((n * 4 + oct) * Ho + iy) * Wo + gx) * 8;
                    hv = *(const half8*)(d1h + ga);
                    lv = *(const half8*)(d1l + ga);
                }
                int base = (row * 50 + xi) * LDSDW + oct * 4;
                *(half8*)((char*)lds + (size_t)base * 4) = hv;
                *(half8*)((char*)lds + ((size_t)PLT8 + base) * 4) = lv;
            }
        }
        __syncthreads();
#pragma unroll
        for (int ky = 0; ky < 3; ++ky) {
#pragma unroll
            for (int kx = 0; kx < 3; ++kx) {
                int tap = ky * 3 + kx;
                const _Float16* bpp = bp + ((size_t)(chunk * 9 + tap) * 2) * 64 * 8;
                half8 bh0 = *(const half8*)(bpp + (size_t)lane * 8);
                half8 bl0 = *(const half8*)(bpp + 27648 + (size_t)lane * 8);
                half8 bh1 = *(const half8*)(bpp + ((size_t)64 + lane) * 8);
                half8 bl1 = *(const half8*)(bpp + 27648 + ((size_t)64 + lane) * 8);
                int row;
                if (chunk < 2) row = ((yr + ky - 1) >> 1) - hh0;
                else           row = wv + ky;
#pragma unroll
                for (int mt = 0; mt < 3; ++mt) {
                    int px = 16 * mt + m;
                    int xi = (chunk < 2) ? (((x0 + px + kx - 1) >> 1) - hx0)
                                         : (px + kx);
                    int adw = (row * 50 + xi) * LDSDW + q * 4;
                    half8 ah = *(const half8*)((const char*)lds + (size_t)adw * 4);
                    half8 al = *(const half8*)((const char*)lds + ((size_t)PLT8 + adw) * 4);
                    acc[mt][0] = __builtin_amdgcn_mfma_f32_16x16x32_f16(ah, bh0, acc[mt][0], 0, 0, 0);
                    acc[mt][0] = __builtin_amdgcn_mfma_f32_16x16x32_f16(ah, bl0, acc[mt][0], 0, 0, 0);
                    acc[mt][0] = __builtin_amdgcn_mfma_f32_16x16x32_f16(al, bh0, acc[mt][0], 0, 0, 0);
                    acc[mt][1] = __builtin_amdgcn_mfma_f32_16x16x32_f16(ah, bh1, acc[mt][1], 0, 0, 0);
                    acc[mt][1] = __builtin_amdgcn_mfma_f32_16x16x32_f16(ah, bl1, acc[mt][1], 0, 0, 0);
                    acc[mt][1] = __builtin_amdgcn_mfma_f32_16x16x32_f16(al, bh1, acc[mt][1], 0, 0, 0);
                }
            }
        }
    }

    float bb0 = b_u2[m], bb1 = b_u2[16 + m];
    float ws0 = w_seg[m], ws1 = w_seg[16 + m];
    float bseg = b_seg[0];
#pragma unroll
    for (int mt = 0; mt < 3; ++mt) {
        float sr[4];
#pragma unroll
        for (int r = 0; r < 4; ++r) {
            float p = ws0 * fmaxf(acc[mt][0][r] + bb0, 0.f)
                    + ws1 * fmaxf(acc[mt][1][r] + bb1, 0.f);
            p += __shfl_xor(p, 1);
            p += __shfl_xor(p, 2);
            p += __shfl_xor(p, 4);
            p += __shfl_xor(p, 8);
            sr[r] = p + bseg;
        }
        if (m == 0) {
            float4 o; o.x = sr[0]; o.y = sr[1]; o.z = sr[2]; o.w = sr[3];
            *(float4*)(seg + ((size_t)n * Ho + yr) * Wo + x0 + 16 * mt + q * 4) = o;
        }
    }
}

// ===========================================================================
// Vector kernels (R18, unchanged).
// ===========================================================================

template <int UPA, int TCO, int SPLIT>
__global__ __launch_bounds__(BS, 2) void conv3x3_x8_kernel(
    const float* __restrict__ inA, int Ca,
    const float* __restrict__ inB, int Cb,
    const float* __restrict__ w, const float* __restrict__ b,
    float* __restrict__ out,
    int N, int H, int W, int Cout, int do_relu,
    _Float16* __restrict__ osph, _Float16* __restrict__ ospl)
{
    const int W8 = W >> 3;
    int idx = blockIdx.x * BS + threadIdx.x;
    int total = N * H * W8;
    if (idx >= total) return;
    int x8 = idx % W8;
    int t  = idx / W8;
    int y  = t % H;
    int n  = t / H;
    int x0 = x8 << 3;
    const int co0 = blockIdx.y * TCO;
    const bool left_ok  = (x0 > 0);
    const bool right_ok = (x0 + 8 < W);
    const int Cin = Ca + Cb;

    float acc[TCO][8];
#pragma unroll
    for (int j = 0; j < TCO; ++j) {
        float bv = b[co0 + j];
#pragma unroll
        for (int p = 0; p < 8; ++p) acc[j][p] = bv;
    }

    for (int ci = 0; ci < Cin; ++ci) {
        float v[3][10];
#pragma unroll
        for (int ky = 0; ky < 3; ++ky) {
            int iy = y + ky - 1;
            if (iy < 0 || iy >= H) {
#pragma unroll
                for (int p = 0; p < 10; ++p) v[ky][p] = 0.f;
                continue;
            }
            if (UPA == 2 && ci < Ca) {
                const float* r = inA + ((size_t)(n * Ca + ci) * (H >> 1) + (iy >> 1)) * (W >> 1);
                int xh = x0 >> 1;
                float sm = left_ok  ? r[xh - 1] : 0.f;
                float4 qq = *(const float4*)(r + xh);
                float s4 = right_ok ? r[xh + 4] : 0.f;
                v[ky][0] = sm;
                v[ky][1] = qq.x; v[ky][2] = qq.x;
                v[ky][3] = qq.y; v[ky][4] = qq.y;
                v[ky][5] = qq.z; v[ky][6] = qq.z;
                v[ky][7] = qq.w; v[ky][8] = qq.w;
                v[ky][9] = s4;
            } else {
                const float* r = (ci < Ca)
                    ? inA + ((size_t)(n * Ca + ci) * H + iy) * W
                    : inB + ((size_t)(n * Cb + (ci - Ca)) * H + iy) * W;
                v[ky][0] = left_ok ? r[x0 - 1] : 0.f;
                float4 q0 = *(const float4*)(r + x0);
                float4 q1 = *(const float4*)(r + x0 + 4);
                v[ky][1] = q0.x; v[ky][2] = q0.y; v[ky][3] = q0.z; v[ky][4] = q0.w;
                v[ky][5] = q1.x; v[ky][6] = q1.y; v[ky][7] = q1.z; v[ky][8] = q1.w;
                v[ky][9] = right_ok ? r[x0 + 8] : 0.f;
            }
        }
#pragma unroll
        for (int j = 0; j < TCO; ++j) {
            const float* wp = w + ((size_t)(co0 + j) * Cin + ci) * 9;
#pragma unroll
            for (int ky = 0; ky < 3; ++ky) {
                float w0 = wp[ky * 3 + 0], w1 = wp[ky * 3 + 1], w2 = wp[ky * 3 + 2];
#pragma unroll
                for (int p = 0; p < 8; ++p)
                    acc[j][p] += w0 * v[ky][p] + w1 * v[ky][p + 1] + w2 * v[ky][p + 2];
            }
        }
    }

    if (SPLIT) {
#pragma unroll
        for (int p = 0; p < 8; ++p) {
            half8 hv, lv;
#pragma unroll
            for (int j = 0; j < 8; ++j) {
                float v = acc[j][p];
                if (do_relu) v = fmaxf(v, 0.f);
                _Float16 hh = (_Float16)v;
                hv[j] = hh;
                lv[j] = (_Float16)(v - (float)hh);
            }
            size_t oaddr = ((size_t)((n * (Cout >> 3) + (co0 >> 3)) * H + y) * W + x0 + p) * 8;
            *(half8*)(osph + oaddr) = hv;
            *(half8*)(ospl + oaddr) = lv;
        }
    } else {
#pragma unroll
        for (int j = 0; j < TCO; ++j) {
#pragma unroll
            for (int p = 0; p < 8; ++p)
                if (do_relu) acc[j][p] = fmaxf(acc[j][p], 0.f);
            float* o = out + ((size_t)(n * Cout + co0 + j) * H + y) * W + x0;
            float4 q0; q0.x = acc[j][0]; q0.y = acc[j][1]; q0.z = acc[j][2]; q0.w = acc[j][3];
            float4 q1; q1.x = acc[j][4]; q1.y = acc[j][5]; q1.z = acc[j][6]; q1.w = acc[j][7];
            *(float4*)o = q0;
            *(float4*)(o + 4) = q1;
        }
    }
}

template <int TCO, int SPLIT>
__global__ __launch_bounds__(BS) void conv3x3_s2_co_kernel(
    const float* __restrict__ inA, int Ca,
    const float* __restrict__ inB, int Cb,
    const float* __restrict__ w, const float* __restrict__ b,
    float* __restrict__ out,
    int N, int Hi, int Wi, int Cout, int do_relu,
    _Float16* __restrict__ osph, _Float16* __restrict__ ospl)
{
    const int Ho = Hi >> 1, Wo = Wi >> 1, Woq = Wo >> 2;
    int idx = blockIdx.x * BS + threadIdx.x;
    int total = N * Ho * Woq;
    if (idx >= total) return;
    int q  = idx % Woq;
    int t  = idx / Woq;
    int oy = t % Ho;
    int n  = t / Ho;
    int ox0 = q << 2;
    int ix0 = ox0 << 1;
    const int co0 = blockIdx.y * TCO;
    const bool right_ok = (ix0 + 8 < Wi);
    const int Cin = Ca + Cb;

    float acc[TCO][4];
#pragma unroll
    for (int j = 0; j < TCO; ++j) {
        float bv = b[co0 + j];
        acc[j][0] = bv; acc[j][1] = bv; acc[j][2] = bv; acc[j][3] = bv;
    }

    for (int ci = 0; ci < Cin; ++ci) {
        const float* base = (ci < Ca)
            ? inA + (size_t)(n * Ca + ci) * Hi * Wi
            : inB + (size_t)(n * Cb + (ci - Ca)) * Hi * Wi;
        float v[3][9];
#pragma unroll
        for (int ky = 0; ky < 3; ++ky) {
            int iy = 2 * oy + ky;
            if (iy >= Hi) {
#pragma unroll
                for (int p = 0; p < 9; ++p) v[ky][p] = 0.f;
                continue;
            }
            const float* r = base + (size_t)iy * Wi + ix0;
            float4 a = *(const float4*)r;
            float4 c = *(const float4*)(r + 4);
            v[ky][0] = a.x; v[ky][1] = a.y; v[ky][2] = a.z; v[ky][3] = a.w;
            v[ky][4] = c.x; v[ky][5] = c.y; v[ky][6] = c.z; v[ky][7] = c.w;
            v[ky][8] = right_ok ? r[8] : 0.f;
        }
#pragma unroll
        for (int j = 0; j < TCO; ++j) {
            const float* wp = w + ((size_t)(co0 + j) * Cin + ci) * 9;
#pragma unroll
            for (int ky = 0; ky < 3; ++ky) {
                float w0 = wp[ky * 3 + 0], w1 = wp[ky * 3 + 1], w2 = wp[ky * 3 + 2];
#pragma unroll
                for (int p = 0; p < 4; ++p)
                    acc[j][p] += w0 * v[ky][2 * p] + w1 * v[ky][2 * p + 1] + w2 * v[ky][2 * p + 2];
            }
        }
    }

    if (SPLIT) {
#pragma unroll
        for (int p = 0; p < 4; ++p) {
            half8 hv, lv;
#pragma unroll
            for (int j = 0; j < 8; ++j) {
                float v = acc[j][p];
                if (do_relu) v = fmaxf(v, 0.f);
                _Float16 hh = (_Float16)v;
                hv[j] = hh;
                lv[j] = (_Float16)(v - (float)hh);
            }
            size_t oaddr = ((size_t)((n * (Cout >> 3) + (co0 >> 3)) * Ho + oy) * Wo + ox0 + p) * 8;
            *(half8*)(osph + oaddr) = hv;
            *(half8*)(ospl + oaddr) = lv;
        }
    } else {
#pragma unroll
        for (int j = 0; j < TCO; ++j) {
            float4 o;
            o.x = acc[j][0]; o.y = acc[j][1]; o.z = acc[j][2]; o.w = acc[j][3];
            if (do_relu) {
                o.x = fmaxf(o.x, 0.f); o.y = fmaxf(o.y, 0.f);
                o.z = fmaxf(o.z, 0.f); o.w = fmaxf(o.w, 0.f);
            }
            *(float4*)(out + ((size_t)(n * Cout + co0 + j) * Ho + oy) * Wo + ox0) = o;
        }
    }
}

__global__ __launch_bounds__(BS) void peaks_kernel(
    const float* __restrict__ hm, float* __restrict__ out,
    int NC, int H, int W, float thresh)
{
    int idx = blockIdx.x * BS + threadIdx.x;
    int total = NC * H * W;
    if (idx >= total) return;
    int x = idx % W;
    int t = idx / W;
    int y = t % H;
    int c = t / H;
    float r = 0.f;
    if (x >= 1 && x < W - 1 && y >= 1 && y < H - 1) {
        const float* base = hm + (size_t)c * H * W;
        float cv = base[y * W + x];
        if (cv > thresh &&
            cv >= base[(y - 1) * W + x] &&
            cv >= base[(y + 1) * W + x] &&
            cv >= base[y * W + (x - 1)] &&
            cv >= base[y * W + (x + 1)])
            r = 1.f;
    }
    out[idx] = r;
}

static inline int nblk(long n) { return (int)((n + BS - 1) / BS); }

extern "C" void kernel_launch(void* const* d_in, const int* in_sizes, int n_in,
                              void* d_out, int out_size, void* d_ws, size_t ws_size,
                              hipStream_t stream)
{
    const float* x     = (const float*)d_in[0];
    const float* w_d1  = (const float*)d_in[1];  const float* b_d1  = (const float*)d_in[2];
    const float* w_d2  = (const float*)d_in[3];  const float* b_d2  = (const float*)d_in[4];
    const float* w_bn  = (const float*)d_in[5];  const float* b_bn  = (const float*)d_in[6];
    const float* w_u1  = (const float*)d_in[7];  const float* b_u1  = (const float*)d_in[8];
    const float* w_u2  = (const float*)d_in[9];  const float* b_u2  = (const float*)d_in[10];
    const float* w_seg = (const float*)d_in[11]; const float* b_seg = (const float*)d_in[12];
    const float* w_p1  = (const float*)d_in[13]; const float* b_p1  = (const float*)d_in[14];
    const float* w_p2  = (const float*)d_in[15]; const float* b_p2  = (const float*)d_in[16];
    const float* w_hm  = (const float*)d_in[17]; const float* b_hm  = (const float*)d_in[18];
    const float* w_paf = (const float*)d_in[19]; const float* b_paf = (const float*)d_in[20];

    const int N = 8, H = 384, W = 384;
    const int H2 = 192, W2 = 192, H4 = 96, W4 = 96;

    float* ws = (float*)d_ws;
    // Lifetime map in header comment.
    _Float16* pd1sp_h = (_Float16*)(ws);               // s1->s3
    _Float16* pd1sp_l = (_Float16*)(ws + 4718592);
    _Float16* d2sp_h = (_Float16*)(ws + 28311552);     // s3->s6
    _Float16* d2sp_l = (_Float16*)(ws + 37748736);
    _Float16* pd2sp_h = (_Float16*)(ws + 47185920);    // s3->s5
    _Float16* pd2sp_l = (_Float16*)(ws + 49545216);
    _Float16* bnsp_h = (_Float16*)(ws + 18874368);     // s5->s6
    _Float16* bnsp_l = (_Float16*)(ws + 23592960);
    _Float16* u1sp_h = (_Float16*)(ws);                // s6->s8
    _Float16* u1sp_l = (_Float16*)(ws + 9437184);
    _Float16* d1sp_h = (_Float16*)(ws + 18874368);     // s7->s8
    _Float16* d1sp_l = (_Float16*)(ws + 37748736);
    _Float16* p1sp_h = (_Float16*)(ws);                // s9->s10
    _Float16* p1sp_l = (_Float16*)(ws + 9437184);
    _Float16* p2sp_h = (_Float16*)(ws + 18874368);     // s10->s12
    _Float16* p2sp_l = (_Float16*)(ws + 23592960);

    float* out_seg   = (float*)d_out;                 // 1179648
    float* out_hm    = out_seg + 1179648;             // 1253376
    float* out_paf   = out_hm + 1253376;              // 2359296
    float* out_peaks = out_paf + 2359296;             // 1253376
    // packed weights in the peaks region [4792320, 6045696), all consumed
    // before step 13 overwrites them. 16B-aligned. (R18 layout)
    _Float16* bp_u1  = (_Float16*)(out_seg + 4792320); // 110592 fl
    _Float16* bp_u2  = (_Float16*)(out_seg + 4902912); // 27648 fl
    _Float16* bp_d2  = (_Float16*)(out_seg + 4930560); // 18432 fl
    _Float16* bp_bn  = (_Float16*)(out_seg + 4948992); // 73728 fl
    _Float16* bp_p2  = (_Float16*)(out_seg + 5022720); // 73728 fl
    _Float16* bp_hm  = (_Float16*)(out_seg + 5096448); // 4096 fl
    _Float16* bp_paf = (_Float16*)(out_seg + 5100544); // 4096 fl -> ends 5104640

    // 0. pack all weights (single launch)
    packw_all_kernel<<<nblk(39040), BS, 0, stream>>>(
        w_u1, w_u2, w_d2, w_bn, w_p2, w_hm, w_paf,
        bp_u1, bp_u2, bp_d2, bp_bn, bp_p2, bp_hm, bp_paf);
    // 1. pd1sp = maxpool_split(relu(conv3x3(x; 3->32))) @384->192  [fused]
    {
        dim3 g(nblk((long)N * H2 * (W / 8)), 32 / 8);
        conv3x3_pool_kernel<8><<<g, BS, 0, stream>>>(
            x, 3, w_d1, b_d1, pd1sp_h, pd1sp_l, N, H, W, 32);
    }
    // 3. d2 = relu(conv3x3(pd1; 32->64)) @192  [MFMA 4x48, 2 exact rounds]
    d2_mfma4_kernel<<<8 * 48 * 4, BS, 0, stream>>>(
        pd1sp_h, pd1sp_l, bp_d2, b_d2, d2sp_h, d2sp_l, pd2sp_h, pd2sp_l);
    // 5. bn = relu(conv3x3(pd2; 64->128)) @96  [MFMA split-in; split-only out]
    conv3x3s_mfma_kernel<2, 8, 96, 96, 1><<<8 * 48 * 3, BS, 0, stream>>>(
        pd2sp_h, pd2sp_l, bp_bn, b_bn, bnsp_h, bnsp_l);
    // 6. u1 = relu(conv3x3(concat(up2(bn), d2); 192->64)) @192  [MFMA 4x48]
    u1_mfma_kernel<<<8 * 48 * 4, BS, 0, stream>>>(
        bnsp_h, bnsp_l, d2sp_h, d2sp_l, bp_u1, b_u1, u1sp_h, u1sp_l);
    // 7. d1' = relu(conv3x3(x; 3->32)) @384  (recompute, split-only out)
    {
        dim3 g(nblk((long)N * H * (W / 8)), 32 / 8);
        conv3x3_x8_kernel<1, 8, 1><<<g, BS, 0, stream>>>(
            x, 3, nullptr, 0, w_d1, b_d1, nullptr, N, H, W, 32, 1, d1sp_h, d1sp_l);
    }
    // 8. seg via fused MFMA u2+seg @384  [MFMA 8x48]
    u2seg_mfma_kernel<<<8 * 48 * 8, BSW, 0, stream>>>(
        u1sp_h, u1sp_l, d1sp_h, d1sp_l, bp_u2, b_u2, w_seg, b_seg, out_seg);
    // 9. p1 = relu(conv3x3_s2(concat(x, seg); 4->64)) @384->192  [vector, split out]
    {
        dim3 g(nblk((long)N * H2 * (W2 / 4)), 64 / 8);
        conv3x3_s2_co_kernel<8, 1><<<g, BS, 0, stream>>>(
            x, 3, out_seg, 1, w_p1, b_p1, nullptr, N, H, W, 64, 1, p1sp_h, p1sp_l);
    }
    // 10. p2 = relu(conv3x3_s2(p1; 64->128)) @192->96  [MFMA s2 split I/O]
    conv3x3s2s_mfma_kernel<2, 8, 192><<<8 * 48 * 3, BS, 0, stream>>>(
        p1sp_h, p1sp_l, bp_p2, b_p2, p2sp_h, p2sp_l);
    // 11+12. hm + paf merged: conv1x1 heads @96  [MFMA, barrier-free A]
    conv1x1_heads_kernel<<<8 * 144, BS, 0, stream>>>(
        p2sp_h, p2sp_l, bp_hm, bp_paf, b_hm, b_paf, out_hm, out_paf, H4 * W4);
    // 13. peaks @96  (overwrites packed-weight region - already consumed)
    peaks_kernel<<<nblk((long)N * 17 * H4 * W4), BS, 0, stream>>>(
        out_hm, out_peaks, N * 17, H4, W4, 0.1f);
}

// Round 13
// 831.843 us; speedup vs baseline: 1.0354x; 1.0354x over previous
//
#include <hip/hip_runtime.h>

// ---------------------------------------------------------------------------
// TeacherModel: small U-Net + pose heads. B=8, H=W=384, fp32 NCHW.
// Round 26: (a) packw merged into the step-1 pool launch (flat 1D grid,
//  branch; bodies verbatim -> bit-identical, -1 launch); (b) p1 TCO 8->16
//  (grid.y 8->4, halves redundant x/seg fetch; per-co accumulation chain
//  unchanged); (c) heads reverted to R24 LDS-staged version (R25's
//  barrier-free variant measured neutral-to-worse).
// R24: d2 4x48 exact-rounds. R23: u1 4x48 exact-rounds. R22: heads merge,
//  pooled epilogues. R21: d1 conv+pool fusion. R18: split planes (hi/lo).
// Workspace lifetime map (floats, 56,623,104 total):
//  pd1sp h/l  [0..4.7M)+[4.7M..9.4M)        s1->s3
//  d2sp h/l   [28.3M..37.7M)+[37.7M..47.2M) s3->s6
//  pd2sp h/l  [47.2M..49.5M)+[49.5M..51.9M) s3->s5
//  bnsp h/l   [18.9M..23.6M)+[23.6M..28.3M) s5->s6
//  u1sp h/l   [0..9.4M)+[9.4M..18.9M)       s6->s8
//  d1sp h/l   [18.9M..37.7M)+[37.7M..56.6M) s7->s8
//  p1sp h/l   [0..9.4M)+[9.4M..18.9M)       s9->s10
//  p2sp h/l   [18.9M..23.6M)+[23.6M..28.3M) s10->s12
// ---------------------------------------------------------------------------

#define BS 256
#define BSW 512     // 8-wave blocks (u2seg)

typedef _Float16 half8 __attribute__((ext_vector_type(8)));
typedef float floatx4 __attribute__((ext_vector_type(4)));

#define LDSDW 20    // dwords per x position
#define PLT8 10000  // 10*50*LDSDW dwords per plane (8-row x 48-px kernels)
#define PLT4 6000   // 6*50*LDSDW dwords per plane (4-row x 48-px kernels)
#define ESTR 388    // 8-row epilogue buffer stride (dw)
#define ESTR4 196   // 4-row epilogue buffer stride (dw): 192+4

// ===========================================================================
// Weight pre-pack device bodies.
// ===========================================================================
__device__ inline void packw_gen_body(
    const float* __restrict__ w, _Float16* __restrict__ bp, int Cin, int Cout,
    int tid, int total)
{
    int lane = tid & 63;
    int t = tid >> 6;
    int NTl = Cout >> 4;
    int nt = t % NTl; t /= NTl;
    int tap = t % 9;
    int chunk = t / 9;
    int q = lane >> 4, n = lane & 15;
    int co = nt * 16 + n;
    _Float16* ph = bp + (size_t)tid * 8;
    _Float16* pl = bp + (size_t)total * 8 + (size_t)tid * 8;
#pragma unroll
    for (int j = 0; j < 8; ++j) {
        int ci = chunk * 32 + q * 8 + j;
        float v = w[((size_t)co * Cin + ci) * 9 + tap];
        _Float16 h = (_Float16)v;
        ph[j] = h;
        pl[j] = (_Float16)(v - (float)h);
    }
}

__device__ inline void packw_1x1_body(
    const float* __restrict__ w, _Float16* __restrict__ bp, int Cin, int NTl, int Cout,
    int tid, int total)
{
    int lane = tid & 63;
    int t = tid >> 6;
    int nt = t % NTl;
    int chunk = t / NTl;
    int q = lane >> 4, n = lane & 15;
    int co = nt * 16 + n;
    _Float16* ph = bp + (size_t)tid * 8;
    _Float16* pl = bp + (size_t)total * 8 + (size_t)tid * 8;
#pragma unroll
    for (int j = 0; j < 8; ++j) {
        int ci = chunk * 32 + q * 8 + j;
        float v = (co < Cout) ? w[(size_t)co * Cin + ci] : 0.f;
        _Float16 h = (_Float16)v;
        ph[j] = h;
        pl[j] = (_Float16)(v - (float)h);
    }
}

// ===========================================================================
// Step 0+1 merged: d1 conv+relu+maxpool (pool blocks) + all weight packs
// (extra blocks). Pool body verbatim from R21's conv3x3_pool_kernel<8>.
// Pool grid flattened: blk < 1152 -> bx = blk%288 (px), by = blk/288 (co oct).
// ===========================================================================
__global__ __launch_bounds__(BS, 2) void pool_packw_kernel(
    const float* __restrict__ inA,
    const float* __restrict__ w, const float* __restrict__ b,
    _Float16* __restrict__ oph, _Float16* __restrict__ opl,
    const float* __restrict__ w_u1, const float* __restrict__ w_u2,
    const float* __restrict__ w_d2, const float* __restrict__ w_bn,
    const float* __restrict__ w_p2, const float* __restrict__ w_hm,
    const float* __restrict__ w_paf,
    _Float16* __restrict__ bp_u1, _Float16* __restrict__ bp_u2,
    _Float16* __restrict__ bp_d2, _Float16* __restrict__ bp_bn,
    _Float16* __restrict__ bp_p2, _Float16* __restrict__ bp_hm,
    _Float16* __restrict__ bp_paf)
{
    const int N = 8, H = 384, W = 384, Cout = 32, Ca = 3;
    const int POOLX = 288;                 // nblk(8*192*48)
    const int POOLBLKS = POOLX * 4;        // grid.y (4 co octs) folded in
    int blk = blockIdx.x;
    if (blk >= POOLBLKS) {
        int tid = (blk - POOLBLKS) * BS + threadIdx.x;
        if (tid < 13824) { packw_gen_body(w_u1, bp_u1, 192, 64, tid, 13824); return; }
        tid -= 13824;
        if (tid < 3456)  { packw_gen_body(w_u2, bp_u2, 96, 32, tid, 3456); return; }
        tid -= 3456;
        if (tid < 2304)  { packw_gen_body(w_d2, bp_d2, 32, 64, tid, 2304); return; }
        tid -= 2304;
        if (tid < 9216)  { packw_gen_body(w_bn, bp_bn, 64, 128, tid, 9216); return; }
        tid -= 9216;
        if (tid < 9216)  { packw_gen_body(w_p2, bp_p2, 64, 128, tid, 9216); return; }
        tid -= 9216;
        if (tid < 512)   { packw_1x1_body(w_hm, bp_hm, 128, 2, 17, tid, 512); return; }
        tid -= 512;
        if (tid < 512)   { packw_1x1_body(w_paf, bp_paf, 128, 2, 32, tid, 512); return; }
        return;
    }

    const int TCO = 8;
    const int W8 = W >> 3;
    const int H2 = H >> 1, W2 = W >> 1;
    int bx = blk % POOLX;
    int by = blk / POOLX;
    int idx = bx * BS + threadIdx.x;
    int total = N * H2 * W8;
    if (idx >= total) return;
    int x8 = idx % W8;
    int t  = idx / W8;
    int yo = t % H2;
    int n  = t / H2;
    int x0 = x8 << 3;
    const int co0 = by * TCO;
    const bool left_ok  = (x0 > 0);
    const bool right_ok = (x0 + 8 < W);
    const int Cin = Ca;

    float pool[TCO][4];

#pragma unroll
    for (int rr = 0; rr < 2; ++rr) {
        int y = 2 * yo + rr;
        float acc[TCO][8];
#pragma unroll
        for (int j = 0; j < TCO; ++j) {
            float bv = b[co0 + j];
#pragma unroll
            for (int p = 0; p < 8; ++p) acc[j][p] = bv;
        }

        for (int ci = 0; ci < Cin; ++ci) {
            float v[3][10];
#pragma unroll
            for (int ky = 0; ky < 3; ++ky) {
                int iy = y + ky - 1;
                if (iy < 0 || iy >= H) {
#pragma unroll
                    for (int p = 0; p < 10; ++p) v[ky][p] = 0.f;
                    continue;
                }
                const float* r = inA + ((size_t)(n * Ca + ci) * H + iy) * W;
                v[ky][0] = left_ok ? r[x0 - 1] : 0.f;
                float4 q0 = *(const float4*)(r + x0);
                float4 q1 = *(const float4*)(r + x0 + 4);
                v[ky][1] = q0.x; v[ky][2] = q0.y; v[ky][3] = q0.z; v[ky][4] = q0.w;
                v[ky][5] = q1.x; v[ky][6] = q1.y; v[ky][7] = q1.z; v[ky][8] = q1.w;
                v[ky][9] = right_ok ? r[x0 + 8] : 0.f;
            }
#pragma unroll
            for (int j = 0; j < TCO; ++j) {
                const float* wp = w + ((size_t)(co0 + j) * Cin + ci) * 9;
#pragma unroll
                for (int ky = 0; ky < 3; ++ky) {
                    float w0 = wp[ky * 3 + 0], w1 = wp[ky * 3 + 1], w2 = wp[ky * 3 + 2];
#pragma unroll
                    for (int p = 0; p < 8; ++p)
                        acc[j][p] += w0 * v[ky][p] + w1 * v[ky][p + 1] + w2 * v[ky][p + 2];
                }
            }
        }

#pragma unroll
        for (int j = 0; j < TCO; ++j) {
#pragma unroll
            for (int p4 = 0; p4 < 4; ++p4) {
                float mrow = fmaxf(fmaxf(acc[j][2 * p4], 0.f),
                                   fmaxf(acc[j][2 * p4 + 1], 0.f));
                pool[j][p4] = (rr == 0) ? mrow : fmaxf(pool[j][p4], mrow);
            }
        }
    }

#pragma unroll
    for (int p4 = 0; p4 < 4; ++p4) {
        half8 hv, lv;
#pragma unroll
        for (int j = 0; j < 8; ++j) {
            float v = pool[j][p4];
            _Float16 h = (_Float16)v;
            hv[j] = h;
            lv[j] = (_Float16)(v - (float)h);
        }
        size_t oa = ((size_t)((n * (Cout >> 3) + (co0 >> 3)) * H2 + yo) * W2
                     + (x0 >> 1) + p4) * 8;
        *(half8*)(oph + oa) = hv;
        *(half8*)(opl + oa) = lv;
    }
}

// ===========================================================================
// Generic stride-1 3x3 SAME conv via MFMA, SPLIT input: block = 2 rows x 32 px.
// OUTMODE: 1 = split only (bn).
// ===========================================================================
template <int CHUNKS, int NT, int HH, int WW, int OUTMODE>
__global__ __launch_bounds__(BS) void conv3x3s_mfma_kernel(
    const _Float16* __restrict__ inh, const _Float16* __restrict__ inl,
    const _Float16* __restrict__ bp,
    const float* __restrict__ bias,
    _Float16* __restrict__ osph,
    _Float16* __restrict__ ospl)
{
    constexpr int PL = 4 * 34 * LDSDW;
    constexpr int EPI = 64 * NT * 16;
    constexpr int LDS_DW = (2 * PL > EPI) ? 2 * PL : EPI;
    __shared__ unsigned int lds[LDS_DW];

    int xblks = WW / 32;
    int b = blockIdx.x;
    int xb = b % xblks; b /= xblks;
    int yp = b % (HH / 2);
    int n  = b / (HH / 2);
    int y0 = yp * 2;
    int x0 = xb * 32;

    int tid = threadIdx.x;
    int lane = tid & 63, wv = tid >> 6;
    int m = lane & 15, q = lane >> 4;
    int lrow = wv >> 1;
    int lx   = (wv & 1) * 16;

    floatx4 acc[NT];
#pragma unroll
    for (int nt = 0; nt < NT; ++nt) acc[nt] = (floatx4){0.f, 0.f, 0.f, 0.f};

    const int planeW = CHUNKS * 9 * NT * 64 * 8;

    for (int chunk = 0; chunk < CHUNKS; ++chunk) {
        __syncthreads();
        for (int e = tid; e < 4 * 34 * 4; e += BS) {
            int xi = e % 34;
            int rest = e / 34;
            int oct = rest & 3;
            int row = rest >> 2;
            int iy = y0 - 1 + row, gx = x0 - 1 + xi;
            half8 hv = {}, lv = {};
            if (iy >= 0 && iy < HH && gx >= 0 && gx < WW) {
                size_t ga = ((size_t)((n * (CHUNKS * 4) + chunk * 4 + oct) * HH + iy) * WW + gx) * 8;
                hv = *(const half8*)(inh + ga);
                lv = *(const half8*)(inl + ga);
            }
            int base = (row * 34 + xi) * LDSDW + oct * 4;
            *(half8*)((char*)lds + (size_t)base * 4) = hv;
            *(half8*)((char*)lds + ((size_t)PL + base) * 4) = lv;
        }
        __syncthreads();
#pragma unroll
        for (int ky = 0; ky < 3; ++ky) {
#pragma unroll
            for (int kx = 0; kx < 3; ++kx) {
                int row = lrow + ky;
                int xi  = lx + m + kx;
                int adw = (row * 34 + xi) * LDSDW + q * 4;
                half8 ah = *(const half8*)((const char*)lds + (size_t)adw * 4);
                half8 al = *(const half8*)((const char*)lds + ((size_t)PL + adw) * 4);
                int tap = ky * 3 + kx;
                const _Float16* bpp = bp + ((size_t)(chunk * 9 + tap) * NT) * 64 * 8;
#pragma unroll
                for (int nt = 0; nt < NT; ++nt) {
                    half8 bh = *(const half8*)(bpp + ((size_t)nt * 64 + lane) * 8);
                    half8 bl = *(const half8*)(bpp + planeW + ((size_t)nt * 64 + lane) * 8);
                    acc[nt] = __builtin_amdgcn_mfma_f32_16x16x32_f16(ah, bh, acc[nt], 0, 0, 0);
                    acc[nt] = __builtin_amdgcn_mfma_f32_16x16x32_f16(ah, bl, acc[nt], 0, 0, 0);
                    acc[nt] = __builtin_amdgcn_mfma_f32_16x16x32_f16(al, bh, acc[nt], 0, 0, 0);
                }
            }
        }
    }

    __syncthreads();
#pragma unroll
    for (int nt = 0; nt < NT; ++nt) {
#pragma unroll
        for (int r = 0; r < 4; ++r) {
            int co = nt * 16 + m;
            int pxl = wv * 16 + q * 4 + r;
            ((float*)lds)[co * 64 + pxl] = acc[nt][r];
        }
    }
    __syncthreads();
    {
        constexpr int OCTS = NT * 2;
        for (int it = tid; it < OCTS * 64; it += BS) {
            int px = it & 63;
            int oct = it >> 6;
            int row = y0 + (px >> 5), xx = x0 + (px & 31);
            half8 hv, lv;
#pragma unroll
            for (int j = 0; j < 8; ++j) {
                float v = fmaxf(((float*)lds)[(oct * 8 + j) * 64 + px] + bias[oct * 8 + j], 0.f);
                _Float16 hh = (_Float16)v;
                hv[j] = hh;
                lv[j] = (_Float16)(v - (float)hh);
            }
            size_t oaddr = ((size_t)((n * OCTS + oct) * HH + row) * WW + xx) * 8;
            *(half8*)(osph + oaddr) = hv;
            *(half8*)(ospl + oaddr) = lv;
        }
    }
}

// ===========================================================================
// d2 = relu(conv3x3(pd1; 32->64)) @192, 4 rows x 48 px (R24: exact rounds).
// ===========================================================================
__global__ __launch_bounds__(BS) void d2_mfma4_kernel(
    const _Float16* __restrict__ inh, const _Float16* __restrict__ inl,  // pd1sp [8,4,192,192,8]
    const _Float16* __restrict__ bp,                                     // bp_d2 (9 taps x 4nt)
    const float* __restrict__ bias,                                      // b_d2 [64]
    _Float16* __restrict__ oh, _Float16* __restrict__ ol_,               // d2sp [8,8,192,192,8]
    _Float16* __restrict__ oph, _Float16* __restrict__ opl)              // pd2sp [8,8,96,96,8]
{
    __shared__ unsigned int lds[2 * PLT4 + 128];
    const int Ho = 192, Wo = 192;
    int b = blockIdx.x;
    int xb = b % 4; b /= 4;
    int yb = b % 48;
    int n  = b / 48;
    int y0 = yb * 4;
    int x0 = xb * 48;

    int tid = threadIdx.x;
    int lane = tid & 63, wv = tid >> 6;               // wv 0..3
    int m = lane & 15, q = lane >> 4;

    floatx4 acc[3][4];
#pragma unroll
    for (int mt = 0; mt < 3; ++mt)
#pragma unroll
        for (int nt = 0; nt < 4; ++nt) acc[mt][nt] = (floatx4){0.f, 0.f, 0.f, 0.f};

    for (int e = tid; e < 6 * 50 * 4; e += BS) {
        int xi = e % 50;
        int rest = e / 50;
        int oct = rest & 3;
        int row = rest >> 2;
        int iy = y0 - 1 + row, gx = x0 - 1 + xi;
        half8 hv = {}, lv = {};
        if (iy >= 0 && iy < Ho && gx >= 0 && gx < Wo) {
            size_t ga = ((size_t)((n * 4 + oct) * Ho + iy) * Wo + gx) * 8;
            hv = *(const half8*)(inh + ga);
            lv = *(const half8*)(inl + ga);
        }
        int base = (row * 50 + xi) * LDSDW + oct * 4;
        *(half8*)((char*)lds + (size_t)base * 4) = hv;
        *(half8*)((char*)lds + ((size_t)PLT4 + base) * 4) = lv;
    }
    __syncthreads();
#pragma unroll
    for (int ky = 0; ky < 3; ++ky) {
#pragma unroll
        for (int kx = 0; kx < 3; ++kx) {
            int tap = ky * 3 + kx;
            const _Float16* bpp = bp + (size_t)tap * 2048;
            half8 bh[4], bl[4];
#pragma unroll
            for (int nt = 0; nt < 4; ++nt) {
                bh[nt] = *(const half8*)(bpp + ((size_t)nt * 64 + lane) * 8);
                bl[nt] = *(const half8*)(bpp + 18432 + ((size_t)nt * 64 + lane) * 8);
            }
            int row = wv + ky;
#pragma unroll
            for (int mt = 0; mt < 3; ++mt) {
                int px = 16 * mt + m;
                int xi = px + kx;
                int adw = (row * 50 + xi) * LDSDW + q * 4;
                half8 ah = *(const half8*)((const char*)lds + (size_t)adw * 4);
                half8 al = *(const half8*)((const char*)lds + ((size_t)PLT4 + adw) * 4);
#pragma unroll
                for (int nt = 0; nt < 4; ++nt) {
                    acc[mt][nt] = __builtin_amdgcn_mfma_f32_16x16x32_f16(ah, bh[nt], acc[mt][nt], 0, 0, 0);
                    acc[mt][nt] = __builtin_amdgcn_mfma_f32_16x16x32_f16(ah, bl[nt], acc[mt][nt], 0, 0, 0);
                    acc[mt][nt] = __builtin_amdgcn_mfma_f32_16x16x32_f16(al, bh[nt], acc[mt][nt], 0, 0, 0);
                }
            }
        }
    }

#pragma unroll
    for (int h = 0; h < 2; ++h) {
        __syncthreads();
#pragma unroll
        for (int ntl = 0; ntl < 2; ++ntl) {
#pragma unroll
            for (int mt = 0; mt < 3; ++mt) {
#pragma unroll
                for (int r = 0; r < 4; ++r) {
                    ((float*)lds)[(ntl * 16 + m) * ESTR4 + wv * 48 + 16 * mt + q * 4 + r]
                        = acc[mt][h * 2 + ntl][r];
                }
            }
        }
        __syncthreads();
        for (int it = tid; it < 4 * 192; it += BS) {
            int px = it % 192;
            int ol = it / 192;
            int row = y0 + px / 48, xx = x0 + px % 48;
            half8 hv, lv;
#pragma unroll
            for (int j = 0; j < 8; ++j) {
                int col = ol * 8 + j;
                float v = fmaxf(((float*)lds)[col * ESTR4 + px] + bias[h * 32 + col], 0.f);
                _Float16 hh = (_Float16)v;
                hv[j] = hh;
                lv[j] = (_Float16)(v - (float)hh);
            }
            size_t oaddr = ((size_t)((n * 8 + h * 4 + ol) * Ho + row) * Wo + xx) * 8;
            *(half8*)(oh + oaddr) = hv;
            *(half8*)(ol_ + oaddr) = lv;
        }
        for (int it = tid; it < 4 * 2 * 24; it += BS) {
            int xo = it % 24;
            int rest = it / 24;
            int ro = rest & 1;
            int ol = rest >> 1;
            half8 hv, lv;
#pragma unroll
            for (int j = 0; j < 8; ++j) {
                int col = ol * 8 + j;
                float bb = bias[h * 32 + col];
                const float* buf = (const float*)lds + col * ESTR4;
                float t0 = fmaxf(fmaxf(buf[(2 * ro) * 48 + 2 * xo] + bb, 0.f),
                                 fmaxf(buf[(2 * ro) * 48 + 2 * xo + 1] + bb, 0.f));
                float t1 = fmaxf(fmaxf(buf[(2 * ro + 1) * 48 + 2 * xo] + bb, 0.f),
                                 fmaxf(buf[(2 * ro + 1) * 48 + 2 * xo + 1] + bb, 0.f));
                float v = fmaxf(t0, t1);
                _Float16 hh = (_Float16)v;
                hv[j] = hh;
                lv[j] = (_Float16)(v - (float)hh);
            }
            size_t oaddr = ((size_t)((n * 8 + h * 4 + ol) * 96 + (yb * 2 + ro)) * 96
                            + (xb * 24 + xo)) * 8;
            *(half8*)(oph + oaddr) = hv;
            *(half8*)(opl + oaddr) = lv;
        }
    }
}

// ===========================================================================
// Stride-2 3x3 conv via MFMA, SPLIT input + SPLIT output (p2).
// ===========================================================================
template <int CHUNKS, int NT, int WI>
__global__ __launch_bounds__(BS) void conv3x3s2s_mfma_kernel(
    const _Float16* __restrict__ inh, const _Float16* __restrict__ inl,
    const _Float16* __restrict__ bp,
    const float* __restrict__ bias,  // [NT*16]
    _Float16* __restrict__ oh, _Float16* __restrict__ ol_)  // [8, NT*2, WO, WO, 8]
{
    constexpr int WO = WI / 2;
    constexpr int PLs = 5 * 68 * LDSDW;
    constexpr int EPI = 64 * NT * 16;
    constexpr int LDS_DW = (2 * PLs > EPI) ? 2 * PLs : EPI;
    __shared__ unsigned int lds[LDS_DW];

    int xblks = WO / 32;
    int b = blockIdx.x;
    int xb = b % xblks; b /= xblks;
    int yp = b % (WO / 2);
    int n  = b / (WO / 2);
    int y0 = yp * 2;
    int x0 = xb * 32;

    int tid = threadIdx.x;
    int lane = tid & 63, wv = tid >> 6;
    int m = lane & 15, q = lane >> 4;
    int lrow = wv >> 1;
    int lx   = (wv & 1) * 16;

    floatx4 acc[NT];
#pragma unroll
    for (int nt = 0; nt < NT; ++nt) acc[nt] = (floatx4){0.f, 0.f, 0.f, 0.f};

    const int planeW = CHUNKS * 9 * NT * 64 * 8;

    for (int chunk = 0; chunk < CHUNKS; ++chunk) {
        __syncthreads();
        for (int e = tid; e < 5 * 68 * 4; e += BS) {
            int xi = e % 68;
            int rest = e / 68;
            int oct = rest & 3;
            int row = rest >> 2;
            int iy = 2 * y0 + row, ix = 2 * x0 + xi;
            half8 hv = {}, lv = {};
            if (xi < 65 && iy < WI && ix < WI) {
                size_t ga = ((size_t)((n * (CHUNKS * 4) + chunk * 4 + oct) * WI + iy) * WI + ix) * 8;
                hv = *(const half8*)(inh + ga);
                lv = *(const half8*)(inl + ga);
            }
            int pos = (xi & 1) * 34 + (xi >> 1);
            int base = (row * 68 + pos) * LDSDW + oct * 4;
            *(half8*)((char*)lds + (size_t)base * 4) = hv;
            *(half8*)((char*)lds + ((size_t)PLs + base) * 4) = lv;
        }
        __syncthreads();
#pragma unroll
        for (int ky = 0; ky < 3; ++ky) {
#pragma unroll
            for (int kx = 0; kx < 3; ++kx) {
                int row = 2 * lrow + ky;
                int pos = (kx & 1) * 34 + (lx + m) + (kx >> 1);
                int adw = (row * 68 + pos) * LDSDW + q * 4;
                half8 ah = *(const half8*)((const char*)lds + (size_t)adw * 4);
                half8 al = *(const half8*)((const char*)lds + ((size_t)PLs + adw) * 4);
                int tap = ky * 3 + kx;
                const _Float16* bpp = bp + ((size_t)(chunk * 9 + tap) * NT) * 64 * 8;
#pragma unroll
                for (int nt = 0; nt < NT; ++nt) {
                    half8 bh = *(const half8*)(bpp + ((size_t)nt * 64 + lane) * 8);
                    half8 bl = *(const half8*)(bpp + planeW + ((size_t)nt * 64 + lane) * 8);
                    acc[nt] = __builtin_amdgcn_mfma_f32_16x16x32_f16(ah, bh, acc[nt], 0, 0, 0);
                    acc[nt] = __builtin_amdgcn_mfma_f32_16x16x32_f16(ah, bl, acc[nt], 0, 0, 0);
                    acc[nt] = __builtin_amdgcn_mfma_f32_16x16x32_f16(al, bh, acc[nt], 0, 0, 0);
                }
            }
        }
    }

    __syncthreads();
#pragma unroll
    for (int nt = 0; nt < NT; ++nt) {
#pragma unroll
        for (int r = 0; r < 4; ++r) {
            int co = nt * 16 + m;
            int pxl = wv * 16 + q * 4 + r;
            ((float*)lds)[co * 64 + pxl] = acc[nt][r];
        }
    }
    __syncthreads();
    {
        constexpr int OCTS = NT * 2;
        for (int it = tid; it < OCTS * 64; it += BS) {
            int px = it & 63;
            int oct = it >> 6;
            int row = y0 + (px >> 5), xx = x0 + (px & 31);
            half8 hv, lv;
#pragma unroll
            for (int j = 0; j < 8; ++j) {
                float v = fmaxf(((float*)lds)[(oct * 8 + j) * 64 + px] + bias[oct * 8 + j], 0.f);
                _Float16 hh = (_Float16)v;
                hv[j] = hh;
                lv[j] = (_Float16)(v - (float)hh);
            }
            size_t oaddr = ((size_t)((n * OCTS + oct) * WO + row) * WO + xx) * 8;
            *(half8*)(oh + oaddr) = hv;
            *(half8*)(ol_ + oaddr) = lv;
        }
    }
}

// ===========================================================================
// Merged heads: hm (17) + paf (32) 1x1 convs over p2sp, one staging pass.
// (R24 LDS-staged version — measured better than the R25 barrier-free one.)
// ===========================================================================
__global__ __launch_bounds__(BS) void conv1x1_heads_kernel(
    const _Float16* __restrict__ inh, const _Float16* __restrict__ inl,  // [8,16,HW,8]
    const _Float16* __restrict__ bph, const _Float16* __restrict__ bpp,  // bp_hm, bp_paf
    const float* __restrict__ bh_, const float* __restrict__ bpf,        // b_hm, b_paf
    float* __restrict__ out_hm, float* __restrict__ out_paf, int HW)
{
    constexpr int PL1 = 64 * LDSDW;                   // 1280 dw
    __shared__ unsigned int lds[64 * 64];

    int pblks = HW / 64;
    int b = blockIdx.x;
    int pb = b % pblks;
    int n  = b / pblks;
    int sp0 = pb * 64;

    int tid = threadIdx.x;
    int lane = tid & 63, wv = tid >> 6;
    int m = lane & 15, q = lane >> 4;

    floatx4 acc[4];
#pragma unroll
    for (int nt = 0; nt < 4; ++nt) acc[nt] = (floatx4){0.f, 0.f, 0.f, 0.f};

    for (int chunk = 0; chunk < 4; ++chunk) {
        __syncthreads();
        {
            int px = tid & 63;
            int oct = tid >> 6;
            size_t ga = (((size_t)(n * 16 + chunk * 4 + oct)) * HW + sp0 + px) * 8;
            half8 hv = *(const half8*)(inh + ga);
            half8 lv = *(const half8*)(inl + ga);
            int base = px * LDSDW + oct * 4;
            *(half8*)((char*)lds + (size_t)base * 4) = hv;
            *(half8*)((char*)lds + ((size_t)PL1 + base) * 4) = lv;
        }
        __syncthreads();
        {
            int adw = (wv * 16 + m) * LDSDW + q * 4;
            half8 ah = *(const half8*)((const char*)lds + (size_t)adw * 4);
            half8 al = *(const half8*)((const char*)lds + ((size_t)PL1 + adw) * 4);
#pragma unroll
            for (int nt = 0; nt < 4; ++nt) {
                const _Float16* base = (nt < 2) ? bph : bpp;
                int ntl = nt & 1;
                const _Float16* pbh = base + (size_t)(chunk * 2 + ntl) * 512 + (size_t)lane * 8;
                half8 bh = *(const half8*)pbh;
                half8 bl = *(const half8*)(pbh + 4096);
                acc[nt] = __builtin_amdgcn_mfma_f32_16x16x32_f16(ah, bh, acc[nt], 0, 0, 0);
                acc[nt] = __builtin_amdgcn_mfma_f32_16x16x32_f16(ah, bl, acc[nt], 0, 0, 0);
                acc[nt] = __builtin_amdgcn_mfma_f32_16x16x32_f16(al, bh, acc[nt], 0, 0, 0);
            }
        }
    }

    __syncthreads();
#pragma unroll
    for (int nt = 0; nt < 4; ++nt) {
#pragma unroll
        for (int r = 0; r < 4; ++r) {
            ((float*)lds)[(nt * 16 + m) * 64 + wv * 16 + q * 4 + r] = acc[nt][r];
        }
    }
    __syncthreads();
    {
        int co = tid >> 2;
        int g  = tid & 3;
        const float* lp = (const float*)lds + co * 64 + g * 16;
        if (co < 17) {
            float bb = bh_[co];
            float* op = out_hm + ((size_t)(n * 17 + co)) * HW + sp0 + g * 16;
#pragma unroll
            for (int u = 0; u < 16; u += 4) {
                float4 vv = *(const float4*)(lp + u);
                vv.x += bb; vv.y += bb; vv.z += bb; vv.w += bb;
                *(float4*)(op + u) = vv;
            }
        } else if (co >= 32) {
            int pco = co - 32;
            float bb = bpf[pco];
            float* op = out_paf + ((size_t)(n * 32 + pco)) * HW + sp0 + g * 16;
#pragma unroll
            for (int u = 0; u < 16; u += 4) {
                float4 vv = *(const float4*)(lp + u);
                vv.x += bb; vv.y += bb; vv.z += bb; vv.w += bb;
                *(float4*)(op + u) = vv;
            }
        }
    }
}

// ===========================================================================
// u1 = relu(conv3x3(concat(up2(bn), d2))) via MFMA, 4 rows x 48 px @192. (R23)
// ===========================================================================
__global__ __launch_bounds__(BS) void u1_mfma_kernel(
    const _Float16* __restrict__ bnh, const _Float16* __restrict__ bnl,  // [8,16,96,96,8]
    const _Float16* __restrict__ d2h, const _Float16* __restrict__ d2l,  // [8,8,192,192,8]
    const _Float16* __restrict__ bp,
    const float* __restrict__ b_u1,  // [64]
    _Float16* __restrict__ oh, _Float16* __restrict__ ol_)               // [8,8,192,192,8]
{
    __shared__ unsigned int lds[2 * PLT4 + 128];
    const int Ho = 192, Wo = 192;
    int b = blockIdx.x;
    int xb = b % 4; b /= 4;
    int yb = b % 48;
    int n  = b / 48;
    int y0 = yb * 4;
    int x0 = xb * 48;

    int tid = threadIdx.x;
    int lane = tid & 63, wv = tid >> 6;               // wv 0..3
    int m = lane & 15, q = lane >> 4;
    int yr = y0 + wv;

    floatx4 acc[3][4];
#pragma unroll
    for (int mt = 0; mt < 3; ++mt)
#pragma unroll
        for (int nt = 0; nt < 4; ++nt) acc[mt][nt] = (floatx4){0.f, 0.f, 0.f, 0.f};

    const int hh0 = (y0 - 1) >> 1;
    const int hx0 = (x0 - 1) >> 1;

    for (int chunk = 0; chunk < 6; ++chunk) {
        __syncthreads();
        if (chunk < 4) {
            for (int e = tid; e < 4 * 26 * 4; e += BS) {
                int xi = e % 26;
                int rest = e / 26;
                int oct = rest & 3;
                int row = rest >> 2;
                int hy = hh0 + row, hx = hx0 + xi;
                half8 hv = {}, lv = {};
                if (hy >= 0 && hy < 96 && hx >= 0 && hx < 96) {
                    size_t ga = ((size_t)((n * 16 + chunk * 4 + oct) * 96 + hy) * 96 + hx) * 8;
                    hv = *(const half8*)(bnh + ga);
                    lv = *(const half8*)(bnl + ga);
                }
                int base = (row * 50 + xi) * LDSDW + oct * 4;
                *(half8*)((char*)lds + (size_t)base * 4) = hv;
                *(half8*)((char*)lds + ((size_t)PLT4 + base) * 4) = lv;
            }
        } else {
            for (int e = tid; e < 6 * 50 * 4; e += BS) {
                int xi = e % 50;
                int rest = e / 50;
                int oct = rest & 3;
                int row = rest >> 2;
                int iy = y0 - 1 + row, gx = x0 - 1 + xi;
                half8 hv = {}, lv = {};
                if (iy >= 0 && iy < Ho && gx >= 0 && gx < Wo) {
                    size_t ga = ((size_t)((n * 8 + (chunk - 4) * 4 + oct) * Ho + iy) * Wo + gx) * 8;
                    hv = *(const half8*)(d2h + ga);
                    lv = *(const half8*)(d2l + ga);
                }
                int base = (row * 50 + xi) * LDSDW + oct * 4;
                *(half8*)((char*)lds + (size_t)base * 4) = hv;
                *(half8*)((char*)lds + ((size_t)PLT4 + base) * 4) = lv;
            }
        }
        __syncthreads();
#pragma unroll
        for (int ky = 0; ky < 3; ++ky) {
#pragma unroll
            for (int kx = 0; kx < 3; ++kx) {
                int tap = ky * 3 + kx;
                const _Float16* bpp = bp + ((size_t)(chunk * 9 + tap) * 4) * 64 * 8;
                half8 bh[4], bl[4];
#pragma unroll
                for (int nt = 0; nt < 4; ++nt) {
                    bh[nt] = *(const half8*)(bpp + ((size_t)nt * 64 + lane) * 8);
                    bl[nt] = *(const half8*)(bpp + 110592 + ((size_t)nt * 64 + lane) * 8);
                }
                int row;
                if (chunk < 4) row = ((yr + ky - 1) >> 1) - hh0;
                else           row = wv + ky;
#pragma unroll
                for (int mt = 0; mt < 3; ++mt) {
                    int px = 16 * mt + m;
                    int xi = (chunk < 4) ? (((x0 + px + kx - 1) >> 1) - hx0)
                                         : (px + kx);
                    int adw = (row * 50 + xi) * LDSDW + q * 4;
                    half8 ah = *(const half8*)((const char*)lds + (size_t)adw * 4);
                    half8 al = *(const half8*)((const char*)lds + ((size_t)PLT4 + adw) * 4);
#pragma unroll
                    for (int nt = 0; nt < 4; ++nt) {
                        acc[mt][nt] = __builtin_amdgcn_mfma_f32_16x16x32_f16(ah, bh[nt], acc[mt][nt], 0, 0, 0);
                        acc[mt][nt] = __builtin_amdgcn_mfma_f32_16x16x32_f16(ah, bl[nt], acc[mt][nt], 0, 0, 0);
                        acc[mt][nt] = __builtin_amdgcn_mfma_f32_16x16x32_f16(al, bh[nt], acc[mt][nt], 0, 0, 0);
                    }
                }
            }
        }
    }

    // epilogue: 2 halves of 32 co; buffer [32 co][stride ESTR4; 192 px used]
#pragma unroll
    for (int h = 0; h < 2; ++h) {
        __syncthreads();
#pragma unroll
        for (int ntl = 0; ntl < 2; ++ntl) {
#pragma unroll
            for (int mt = 0; mt < 3; ++mt) {
#pragma unroll
                for (int r = 0; r < 4; ++r) {
                    ((float*)lds)[(ntl * 16 + m) * ESTR4 + wv * 48 + 16 * mt + q * 4 + r]
                        = acc[mt][h * 2 + ntl][r];
                }
            }
        }
        __syncthreads();
        for (int it = tid; it < 4 * 192; it += BS) {
            int px = it % 192;
            int ol = it / 192;
            int row = y0 + px / 48, xx = x0 + px % 48;
            half8 hv, lv;
#pragma unroll
            for (int j = 0; j < 8; ++j) {
                int col = ol * 8 + j;
                float v = fmaxf(((float*)lds)[col * ESTR4 + px] + b_u1[h * 32 + col], 0.f);
                _Float16 hh = (_Float16)v;
                hv[j] = hh;
                lv[j] = (_Float16)(v - (float)hh);
            }
            size_t oaddr = ((size_t)((n * 8 + h * 4 + ol) * Ho + row) * Wo + xx) * 8;
            *(half8*)(oh + oaddr) = hv;
            *(half8*)(ol_ + oaddr) = lv;
        }
    }
}

// ===========================================================================
// seg via fused MFMA u2+seg, 8 rows x 48 px @384; shfl_xor co-reduce. (R18)
// ===========================================================================
__global__ __launch_bounds__(BSW) void u2seg_mfma_kernel(
    const _Float16* __restrict__ u1h, const _Float16* __restrict__ u1l,  // [8,8,192,192,8]
    const _Float16* __restrict__ d1h, const _Float16* __restrict__ d1l,  // [8,4,384,384,8]
    const _Float16* __restrict__ bp,
    const float* __restrict__ b_u2,  // [32]
    const float* __restrict__ w_seg, // [32]
    const float* __restrict__ b_seg, // [1]
    float* __restrict__ seg)         // [8,1,384,384]
{
    __shared__ unsigned int lds[2 * PLT8];
    const int Ho = 384, Wo = 384;
    int b = blockIdx.x;
    int xb = b % 8; b /= 8;
    int yb = b % 48;
    int n  = b / 48;
    int y0 = yb * 8;
    int x0 = xb * 48;

    int tid = threadIdx.x;
    int lane = tid & 63, wv = tid >> 6;
    int m = lane & 15, q = lane >> 4;
    int yr = y0 + wv;

    floatx4 acc[3][2];
#pragma unroll
    for (int mt = 0; mt < 3; ++mt) {
        acc[mt][0] = (floatx4){0.f, 0.f, 0.f, 0.f};
        acc[mt][1] = (floatx4){0.f, 0.f, 0.f, 0.f};
    }

    const int hh0 = (y0 - 1) >> 1;
    const int hx0 = (x0 - 1) >> 1;

    for (int chunk = 0; chunk < 3; ++chunk) {
        __syncthreads();
        if (chunk < 2) {
            for (int e = tid; e < 6 * 26 * 4; e += BSW) {
                int xi = e % 26;
                int rest = e / 26;
                int oct = rest & 3;
                int row = rest >> 2;
                int hy = hh0 + row, hx = hx0 + xi;
                half8 hv = {}, lv = {};
                if (hy >= 0 && hy < 192 && hx >= 0 && hx < 192) {
                    size_t ga = ((size_t)((n * 8 + chunk * 4 + oct) * 192 + hy) * 192 + hx) * 8;
                    hv = *(const half8*)(u1h + ga);
                    lv = *(const half8*)(u1l + ga);
                }
                int base = (row * 50 + xi) * LDSDW + oct * 4;
                *(half8*)((char*)lds + (size_t)base * 4) = hv;
                *(half8*)((char*)lds + ((size_t)PLT8 + base) * 4) = lv;
            }
        } else {
            for (int e = tid; e < 10 * 50 * 4; e += BSW) {
                int xi = e % 50;
                int rest = e / 50;
                int oct = rest & 3;
                int row = rest >> 2;
                int iy = y0 - 1 + row, gx = x0 - 1 + xi;
                half8 hv = {}, lv = {};
                if (iy >= 0 && iy < Ho && gx >= 0 && gx < Wo) {
                    size_t ga = ((size_t)((n * 4 + oct) * Ho + iy) * Wo + gx) * 8;
                    hv = *(const half8*)(d1h + ga);
                    lv = *(const half8*)(d1l + ga);
                }
                int base = (row * 50 + xi) * LDSDW + oct * 4;
                *(half8*)((char*)lds + (size_t)base * 4) = hv;
                *(half8*)((char*)lds + ((size_t)PLT8 + base) * 4) = lv;
            }
        }
        __syncthreads();
#pragma unroll
        for (int ky = 0; ky < 3; ++ky) {
#pragma unroll
            for (int kx = 0; kx < 3; ++kx) {
                int tap = ky * 3 + kx;
                const _Float16* bpp = bp + ((size_t)(chunk * 9 + tap) * 2) * 64 * 8;
                half8 bh0 = *(const half8*)(bpp + (size_t)lane * 8);
                half8 bl0 = *(const half8*)(bpp + 27648 + (size_t)lane * 8);
                half8 bh1 = *(const half8*)(bpp + ((size_t)64 + lane) * 8);
                half8 bl1 = *(const half8*)(bpp + 27648 + ((size_t)64 + lane) * 8);
                int row;
                if (chunk < 2) row = ((yr + ky - 1) >> 1) - hh0;
                else           row = wv + ky;
#pragma unroll
                for (int mt = 0; mt < 3; ++mt) {
                    int px = 16 * mt + m;
                    int xi = (chunk < 2) ? (((x0 + px + kx - 1) >> 1) - hx0)
                                         : (px + kx);
                    int adw = (row * 50 + xi) * LDSDW + q * 4;
                    half8 ah = *(const half8*)((const char*)lds + (size_t)adw * 4);
                    half8 al = *(const half8*)((const char*)lds + ((size_t)PLT8 + adw) * 4);
                    acc[mt][0] = __builtin_amdgcn_mfma_f32_16x16x32_f16(ah, bh0, acc[mt][0], 0, 0, 0);
                    acc[mt][0] = __builtin_amdgcn_mfma_f32_16x16x32_f16(ah, bl0, acc[mt][0], 0, 0, 0);
                    acc[mt][0] = __builtin_amdgcn_mfma_f32_16x16x32_f16(al, bh0, acc[mt][0], 0, 0, 0);
                    acc[mt][1] = __builtin_amdgcn_mfma_f32_16x16x32_f16(ah, bh1, acc[mt][1], 0, 0, 0);
                    acc[mt][1] = __builtin_amdgcn_mfma_f32_16x16x32_f16(ah, bl1, acc[mt][1], 0, 0, 0);
                    acc[mt][1] = __builtin_amdgcn_mfma_f32_16x16x32_f16(al, bh1, acc[mt][1], 0, 0, 0);
                }
            }
        }
    }

    float bb0 = b_u2[m], bb1 = b_u2[16 + m];
    float ws0 = w_seg[m], ws1 = w_seg[16 + m];
    float bseg = b_seg[0];
#pragma unroll
    for (int mt = 0; mt < 3; ++mt) {
        float sr[4];
#pragma unroll
        for (int r = 0; r < 4; ++r) {
            float p = ws0 * fmaxf(acc[mt][0][r] + bb0, 0.f)
                    + ws1 * fmaxf(acc[mt][1][r] + bb1, 0.f);
            p += __shfl_xor(p, 1);
            p += __shfl_xor(p, 2);
            p += __shfl_xor(p, 4);
            p += __shfl_xor(p, 8);
            sr[r] = p + bseg;
        }
        if (m == 0) {
            float4 o; o.x = sr[0]; o.y = sr[1]; o.z = sr[2]; o.w = sr[3];
            *(float4*)(seg + ((size_t)n * Ho + yr) * Wo + x0 + 16 * mt + q * 4) = o;
        }
    }
}

// ===========================================================================
// Vector kernels.
// ===========================================================================

template <int UPA, int TCO, int SPLIT>
__global__ __launch_bounds__(BS, 2) void conv3x3_x8_kernel(
    const float* __restrict__ inA, int Ca,
    const float* __restrict__ inB, int Cb,
    const float* __restrict__ w, const float* __restrict__ b,
    float* __restrict__ out,
    int N, int H, int W, int Cout, int do_relu,
    _Float16* __restrict__ osph, _Float16* __restrict__ ospl)
{
    const int W8 = W >> 3;
    int idx = blockIdx.x * BS + threadIdx.x;
    int total = N * H * W8;
    if (idx >= total) return;
    int x8 = idx % W8;
    int t  = idx / W8;
    int y  = t % H;
    int n  = t / H;
    int x0 = x8 << 3;
    const int co0 = blockIdx.y * TCO;
    const bool left_ok  = (x0 > 0);
    const bool right_ok = (x0 + 8 < W);
    const int Cin = Ca + Cb;

    float acc[TCO][8];
#pragma unroll
    for (int j = 0; j < TCO; ++j) {
        float bv = b[co0 + j];
#pragma unroll
        for (int p = 0; p < 8; ++p) acc[j][p] = bv;
    }

    for (int ci = 0; ci < Cin; ++ci) {
        float v[3][10];
#pragma unroll
        for (int ky = 0; ky < 3; ++ky) {
            int iy = y + ky - 1;
            if (iy < 0 || iy >= H) {
#pragma unroll
                for (int p = 0; p < 10; ++p) v[ky][p] = 0.f;
                continue;
            }
            if (UPA == 2 && ci < Ca) {
                const float* r = inA + ((size_t)(n * Ca + ci) * (H >> 1) + (iy >> 1)) * (W >> 1);
                int xh = x0 >> 1;
                float sm = left_ok  ? r[xh - 1] : 0.f;
                float4 qq = *(const float4*)(r + xh);
                float s4 = right_ok ? r[xh + 4] : 0.f;
                v[ky][0] = sm;
                v[ky][1] = qq.x; v[ky][2] = qq.x;
                v[ky][3] = qq.y; v[ky][4] = qq.y;
                v[ky][5] = qq.z; v[ky][6] = qq.z;
                v[ky][7] = qq.w; v[ky][8] = qq.w;
                v[ky][9] = s4;
            } else {
                const float* r = (ci < Ca)
                    ? inA + ((size_t)(n * Ca + ci) * H + iy) * W
                    : inB + ((size_t)(n * Cb + (ci - Ca)) * H + iy) * W;
                v[ky][0] = left_ok ? r[x0 - 1] : 0.f;
                float4 q0 = *(const float4*)(r + x0);
                float4 q1 = *(const float4*)(r + x0 + 4);
                v[ky][1] = q0.x; v[ky][2] = q0.y; v[ky][3] = q0.z; v[ky][4] = q0.w;
                v[ky][5] = q1.x; v[ky][6] = q1.y; v[ky][7] = q1.z; v[ky][8] = q1.w;
                v[ky][9] = right_ok ? r[x0 + 8] : 0.f;
            }
        }
#pragma unroll
        for (int j = 0; j < TCO; ++j) {
            const float* wp = w + ((size_t)(co0 + j) * Cin + ci) * 9;
#pragma unroll
            for (int ky = 0; ky < 3; ++ky) {
                float w0 = wp[ky * 3 + 0], w1 = wp[ky * 3 + 1], w2 = wp[ky * 3 + 2];
#pragma unroll
                for (int p = 0; p < 8; ++p)
                    acc[j][p] += w0 * v[ky][p] + w1 * v[ky][p + 1] + w2 * v[ky][p + 2];
            }
        }
    }

    if (SPLIT) {
#pragma unroll
        for (int oo = 0; oo < TCO / 8; ++oo) {
#pragma unroll
            for (int p = 0; p < 8; ++p) {
                half8 hv, lv;
#pragma unroll
                for (int j = 0; j < 8; ++j) {
                    float v = acc[oo * 8 + j][p];
                    if (do_relu) v = fmaxf(v, 0.f);
                    _Float16 hh = (_Float16)v;
                    hv[j] = hh;
                    lv[j] = (_Float16)(v - (float)hh);
                }
                size_t oaddr = ((size_t)((n * (Cout >> 3) + (co0 >> 3) + oo) * H + y) * W + x0 + p) * 8;
                *(half8*)(osph + oaddr) = hv;
                *(half8*)(ospl + oaddr) = lv;
            }
        }
    } else {
#pragma unroll
        for (int j = 0; j < TCO; ++j) {
#pragma unroll
            for (int p = 0; p < 8; ++p)
                if (do_relu) acc[j][p] = fmaxf(acc[j][p], 0.f);
            float* o = out + ((size_t)(n * Cout + co0 + j) * H + y) * W + x0;
            float4 q0; q0.x = acc[j][0]; q0.y = acc[j][1]; q0.z = acc[j][2]; q0.w = acc[j][3];
            float4 q1; q1.x = acc[j][4]; q1.y = acc[j][5]; q1.z = acc[j][6]; q1.w = acc[j][7];
            *(float4*)o = q0;
            *(float4*)(o + 4) = q1;
        }
    }
}

// p1: stride-2 vector conv with SPLIT output; TCO generalized (R26: TCO=16).
template <int TCO, int SPLIT>
__global__ __launch_bounds__(BS) void conv3x3_s2_co_kernel(
    const float* __restrict__ inA, int Ca,
    const float* __restrict__ inB, int Cb,
    const float* __restrict__ w, const float* __restrict__ b,
    float* __restrict__ out,
    int N, int Hi, int Wi, int Cout, int do_relu,
    _Float16* __restrict__ osph, _Float16* __restrict__ ospl)
{
    const int Ho = Hi >> 1, Wo = Wi >> 1, Woq = Wo >> 2;
    int idx = blockIdx.x * BS + threadIdx.x;
    int total = N * Ho * Woq;
    if (idx >= total) return;
    int q  = idx % Woq;
    int t  = idx / Woq;
    int oy = t % Ho;
    int n  = t / Ho;
    int ox0 = q << 2;
    int ix0 = ox0 << 1;
    const int co0 = blockIdx.y * TCO;
    const bool right_ok = (ix0 + 8 < Wi);
    const int Cin = Ca + Cb;

    float acc[TCO][4];
#pragma unroll
    for (int j = 0; j < TCO; ++j) {
        float bv = b[co0 + j];
        acc[j][0] = bv; acc[j][1] = bv; acc[j][2] = bv; acc[j][3] = bv;
    }

    for (int ci = 0; ci < Cin; ++ci) {
        const float* base = (ci < Ca)
            ? inA + (size_t)(n * Ca + ci) * Hi * Wi
            : inB + (size_t)(n * Cb + (ci - Ca)) * Hi * Wi;
        float v[3][9];
#pragma unroll
        for (int ky = 0; ky < 3; ++ky) {
            int iy = 2 * oy + ky;
            if (iy >= Hi) {
#pragma unroll
                for (int p = 0; p < 9; ++p) v[ky][p] = 0.f;
                continue;
            }
            const float* r = base + (size_t)iy * Wi + ix0;
            float4 a = *(const float4*)r;
            float4 c = *(const float4*)(r + 4);
            v[ky][0] = a.x; v[ky][1] = a.y; v[ky][2] = a.z; v[ky][3] = a.w;
            v[ky][4] = c.x; v[ky][5] = c.y; v[ky][6] = c.z; v[ky][7] = c.w;
            v[ky][8] = right_ok ? r[8] : 0.f;
        }
#pragma unroll
        for (int j = 0; j < TCO; ++j) {
            const float* wp = w + ((size_t)(co0 + j) * Cin + ci) * 9;
#pragma unroll
            for (int ky = 0; ky < 3; ++ky) {
                float w0 = wp[ky * 3 + 0], w1 = wp[ky * 3 + 1], w2 = wp[ky * 3 + 2];
#pragma unroll
                for (int p = 0; p < 4; ++p)
                    acc[j][p] += w0 * v[ky][2 * p] + w1 * v[ky][2 * p + 1] + w2 * v[ky][2 * p + 2];
            }
        }
    }

    if (SPLIT) {
#pragma unroll
        for (int oo = 0; oo < TCO / 8; ++oo) {
#pragma unroll
            for (int p = 0; p < 4; ++p) {
                half8 hv, lv;
#pragma unroll
                for (int j = 0; j < 8; ++j) {
                    float v = acc[oo * 8 + j][p];
                    if (do_relu) v = fmaxf(v, 0.f);
                    _Float16 hh = (_Float16)v;
                    hv[j] = hh;
                    lv[j] = (_Float16)(v - (float)hh);
                }
                size_t oaddr = ((size_t)((n * (Cout >> 3) + (co0 >> 3) + oo) * Ho + oy) * Wo + ox0 + p) * 8;
                *(half8*)(osph + oaddr) = hv;
                *(half8*)(ospl + oaddr) = lv;
            }
        }
    } else {
#pragma unroll
        for (int j = 0; j < TCO; ++j) {
            float4 o;
            o.x = acc[j][0]; o.y = acc[j][1]; o.z = acc[j][2]; o.w = acc[j][3];
            if (do_relu) {
                o.x = fmaxf(o.x, 0.f); o.y = fmaxf(o.y, 0.f);
                o.z = fmaxf(o.z, 0.f); o.w = fmaxf(o.w, 0.f);
            }
            *(float4*)(out + ((size_t)(n * Cout + co0 + j) * Ho + oy) * Wo + ox0) = o;
        }
    }
}

__global__ __launch_bounds__(BS) void peaks_kernel(
    const float* __restrict__ hm, float* __restrict__ out,
    int NC, int H, int W, float thresh)
{
    int idx = blockIdx.x * BS + threadIdx.x;
    int total = NC * H * W;
    if (idx >= total) return;
    int x = idx % W;
    int t = idx / W;
    int y = t % H;
    int c = t / H;
    float r = 0.f;
    if (x >= 1 && x < W - 1 && y >= 1 && y < H - 1) {
        const float* base = hm + (size_t)c * H * W;
        float cv = base[y * W + x];
        if (cv > thresh &&
            cv >= base[(y - 1) * W + x] &&
            cv >= base[(y + 1) * W + x] &&
            cv >= base[y * W + (x - 1)] &&
            cv >= base[y * W + (x + 1)])
            r = 1.f;
    }
    out[idx] = r;
}

static inline int nblk(long n) { return (int)((n + BS - 1) / BS); }

extern "C" void kernel_launch(void* const* d_in, const int* in_sizes, int n_in,
                              void* d_out, int out_size, void* d_ws, size_t ws_size,
                              hipStream_t stream)
{
    const float* x     = (const float*)d_in[0];
    const float* w_d1  = (const float*)d_in[1];  const float* b_d1  = (const float*)d_in[2];
    const float* w_d2  = (const float*)d_in[3];  const float* b_d2  = (const float*)d_in[4];
    const float* w_bn  = (const float*)d_in[5];  const float* b_bn  = (const float*)d_in[6];
    const float* w_u1  = (const float*)d_in[7];  const float* b_u1  = (const float*)d_in[8];
    const float* w_u2  = (const float*)d_in[9];  const float* b_u2  = (const float*)d_in[10];
    const float* w_seg = (const float*)d_in[11]; const float* b_seg = (const float*)d_in[12];
    const float* w_p1  = (const float*)d_in[13]; const float* b_p1  = (const float*)d_in[14];
    const float* w_p2  = (const float*)d_in[15]; const float* b_p2  = (const float*)d_in[16];
    const float* w_hm  = (const float*)d_in[17]; const float* b_hm  = (const float*)d_in[18];
    const float* w_paf = (const float*)d_in[19]; const float* b_paf = (const float*)d_in[20];

    const int N = 8, H = 384, W = 384;
    const int H2 = 192, W2 = 192, H4 = 96, W4 = 96;

    float* ws = (float*)d_ws;
    // Lifetime map in header comment.
    _Float16* pd1sp_h = (_Float16*)(ws);               // s1->s3
    _Float16* pd1sp_l = (_Float16*)(ws + 4718592);
    _Float16* d2sp_h = (_Float16*)(ws + 28311552);     // s3->s6
    _Float16* d2sp_l = (_Float16*)(ws + 37748736);
    _Float16* pd2sp_h = (_Float16*)(ws + 47185920);    // s3->s5
    _Float16* pd2sp_l = (_Float16*)(ws + 49545216);
    _Float16* bnsp_h = (_Float16*)(ws + 18874368);     // s5->s6
    _Float16* bnsp_l = (_Float16*)(ws + 23592960);
    _Float16* u1sp_h = (_Float16*)(ws);                // s6->s8
    _Float16* u1sp_l = (_Float16*)(ws + 9437184);
    _Float16* d1sp_h = (_Float16*)(ws + 18874368);     // s7->s8
    _Float16* d1sp_l = (_Float16*)(ws + 37748736);
    _Float16* p1sp_h = (_Float16*)(ws);                // s9->s10
    _Float16* p1sp_l = (_Float16*)(ws + 9437184);
    _Float16* p2sp_h = (_Float16*)(ws + 18874368);     // s10->s12
    _Float16* p2sp_l = (_Float16*)(ws + 23592960);

    float* out_seg   = (float*)d_out;                 // 1179648
    float* out_hm    = out_seg + 1179648;             // 1253376
    float* out_paf   = out_hm + 1253376;              // 2359296
    float* out_peaks = out_paf + 2359296;             // 1253376
    // packed weights in the peaks region [4792320, 6045696), all consumed
    // before step 13 overwrites them. 16B-aligned. (R18 layout)
    _Float16* bp_u1  = (_Float16*)(out_seg + 4792320); // 110592 fl
    _Float16* bp_u2  = (_Float16*)(out_seg + 4902912); // 27648 fl
    _Float16* bp_d2  = (_Float16*)(out_seg + 4930560); // 18432 fl
    _Float16* bp_bn  = (_Float16*)(out_seg + 4948992); // 73728 fl
    _Float16* bp_p2  = (_Float16*)(out_seg + 5022720); // 73728 fl
    _Float16* bp_hm  = (_Float16*)(out_seg + 5096448); // 4096 fl
    _Float16* bp_paf = (_Float16*)(out_seg + 5100544); // 4096 fl -> ends 5104640

    // 0+1. pool (d1 conv+relu+maxpool -> pd1sp) + all weight packs, one launch
    pool_packw_kernel<<<1152 + 153, BS, 0, stream>>>(
        x, w_d1, b_d1, pd1sp_h, pd1sp_l,
        w_u1, w_u2, w_d2, w_bn, w_p2, w_hm, w_paf,
        bp_u1, bp_u2, bp_d2, bp_bn, bp_p2, bp_hm, bp_paf);
    // 3. d2 = relu(conv3x3(pd1; 32->64)) @192  [MFMA 4x48, 2 exact rounds]
    d2_mfma4_kernel<<<8 * 48 * 4, BS, 0, stream>>>(
        pd1sp_h, pd1sp_l, bp_d2, b_d2, d2sp_h, d2sp_l, pd2sp_h, pd2sp_l);
    // 5. bn = relu(conv3x3(pd2; 64->128)) @96  [MFMA split-in; split-only out]
    conv3x3s_mfma_kernel<2, 8, 96, 96, 1><<<8 * 48 * 3, BS, 0, stream>>>(
        pd2sp_h, pd2sp_l, bp_bn, b_bn, bnsp_h, bnsp_l);
    // 6. u1 = relu(conv3x3(concat(up2(bn), d2); 192->64)) @192  [MFMA 4x48]
    u1_mfma_kernel<<<8 * 48 * 4, BS, 0, stream>>>(
        bnsp_h, bnsp_l, d2sp_h, d2sp_l, bp_u1, b_u1, u1sp_h, u1sp_l);
    // 7. d1' = relu(conv3x3(x; 3->32)) @384  (recompute, split-only out)
    {
        dim3 g(nblk((long)N * H * (W / 8)), 32 / 8);
        conv3x3_x8_kernel<1, 8, 1><<<g, BS, 0, stream>>>(
            x, 3, nullptr, 0, w_d1, b_d1, nullptr, N, H, W, 32, 1, d1sp_h, d1sp_l);
    }
    // 8. seg via fused MFMA u2+seg @384  [MFMA 8x48]
    u2seg_mfma_kernel<<<8 * 48 * 8, BSW, 0, stream>>>(
        u1sp_h, u1sp_l, d1sp_h, d1sp_l, bp_u2, b_u2, w_seg, b_seg, out_seg);
    // 9. p1 = relu(conv3x3_s2(concat(x, seg); 4->64)) @384->192  [vector TCO16]
    {
        dim3 g(nblk((long)N * H2 * (W2 / 4)), 64 / 16);
        conv3x3_s2_co_kernel<16, 1><<<g, BS, 0, stream>>>(
            x, 3, out_seg, 1, w_p1, b_p1, nullptr, N, H, W, 64, 1, p1sp_h, p1sp_l);
    }
    // 10. p2 = relu(conv3x3_s2(p1; 64->128)) @192->96  [MFMA s2 split I/O]
    conv3x3s2s_mfma_kernel<2, 8, 192><<<8 * 48 * 3, BS, 0, stream>>>(
        p1sp_h, p1sp_l, bp_p2, b_p2, p2sp_h, p2sp_l);
    // 11+12. hm + paf merged: conv1x1 heads @96  [MFMA, one staging pass]
    conv1x1_heads_kernel<<<8 * 144, BS, 0, stream>>>(
        p2sp_h, p2sp_l, bp_hm, bp_paf, b_hm, b_paf, out_hm, out_paf, H4 * W4);
    // 13. peaks @96  (overwrites packed-weight region - already consumed)
    peaks_kernel<<<nblk((long)N * 17 * H4 * W4), BS, 0, stream>>>(
        out_hm, out_peaks, N * 17, H4, W4, 0.1f);
}

// Round 14
// 826.431 us; speedup vs baseline: 1.0422x; 1.0065x over previous
//
#include <hip/hip_runtime.h>

// ---------------------------------------------------------------------------
// TeacherModel: small U-Net + pose heads. B=8, H=W=384, fp32 NCHW.
// Round 27: p2 LDS stride trim 68 -> 66. Parity-split reads only touch pos
//  {0..32}u{34..65}; pos 33/66 are unread zero-writes, pos 67 unused. With
//  stride 66 the staged planes drop to 52,800 B -> 3 blocks/CU (was 2),
//  grid 1152: capacity 512 -> 768 (2.25 -> 1.5 rounds). Stores guarded with
//  pos < 66 (skips only never-read zero-writes) -> bit-identical.
// R26: pool+packw merge, p1 TCO16. R24/R23: d2/u1 4x48 exact rounds.
// R22: heads merge, pooled epilogues. R21: d1 conv+pool fusion.
// R18: split planes [C/8][H][W][8] (hi/lo), producer-side.
// Workspace lifetime map (floats, 56,623,104 total):
//  pd1sp h/l  [0..4.7M)+[4.7M..9.4M)        s1->s3
//  d2sp h/l   [28.3M..37.7M)+[37.7M..47.2M) s3->s6
//  pd2sp h/l  [47.2M..49.5M)+[49.5M..51.9M) s3->s5
//  bnsp h/l   [18.9M..23.6M)+[23.6M..28.3M) s5->s6
//  u1sp h/l   [0..9.4M)+[9.4M..18.9M)       s6->s8
//  d1sp h/l   [18.9M..37.7M)+[37.7M..56.6M) s7->s8
//  p1sp h/l   [0..9.4M)+[9.4M..18.9M)       s9->s10
//  p2sp h/l   [18.9M..23.6M)+[23.6M..28.3M) s10->s12
// ---------------------------------------------------------------------------

#define BS 256
#define BSW 512     // 8-wave blocks (u2seg)

typedef _Float16 half8 __attribute__((ext_vector_type(8)));
typedef float floatx4 __attribute__((ext_vector_type(4)));

#define LDSDW 20    // dwords per x position
#define PLT8 10000  // 10*50*LDSDW dwords per plane (8-row x 48-px kernels)
#define PLT4 6000   // 6*50*LDSDW dwords per plane (4-row x 48-px kernels)
#define ESTR 388    // 8-row epilogue buffer stride (dw)
#define ESTR4 196   // 4-row epilogue buffer stride (dw): 192+4

// ===========================================================================
// Weight pre-pack device bodies.
// ===========================================================================
__device__ inline void packw_gen_body(
    const float* __restrict__ w, _Float16* __restrict__ bp, int Cin, int Cout,
    int tid, int total)
{
    int lane = tid & 63;
    int t = tid >> 6;
    int NTl = Cout >> 4;
    int nt = t % NTl; t /= NTl;
    int tap = t % 9;
    int chunk = t / 9;
    int q = lane >> 4, n = lane & 15;
    int co = nt * 16 + n;
    _Float16* ph = bp + (size_t)tid * 8;
    _Float16* pl = bp + (size_t)total * 8 + (size_t)tid * 8;
#pragma unroll
    for (int j = 0; j < 8; ++j) {
        int ci = chunk * 32 + q * 8 + j;
        float v = w[((size_t)co * Cin + ci) * 9 + tap];
        _Float16 h = (_Float16)v;
        ph[j] = h;
        pl[j] = (_Float16)(v - (float)h);
    }
}

__device__ inline void packw_1x1_body(
    const float* __restrict__ w, _Float16* __restrict__ bp, int Cin, int NTl, int Cout,
    int tid, int total)
{
    int lane = tid & 63;
    int t = tid >> 6;
    int nt = t % NTl;
    int chunk = t / NTl;
    int q = lane >> 4, n = lane & 15;
    int co = nt * 16 + n;
    _Float16* ph = bp + (size_t)tid * 8;
    _Float16* pl = bp + (size_t)total * 8 + (size_t)tid * 8;
#pragma unroll
    for (int j = 0; j < 8; ++j) {
        int ci = chunk * 32 + q * 8 + j;
        float v = (co < Cout) ? w[(size_t)co * Cin + ci] : 0.f;
        _Float16 h = (_Float16)v;
        ph[j] = h;
        pl[j] = (_Float16)(v - (float)h);
    }
}

// ===========================================================================
// Step 0+1 merged: d1 conv+relu+maxpool (pool blocks) + all weight packs. (R26)
// ===========================================================================
__global__ __launch_bounds__(BS, 2) void pool_packw_kernel(
    const float* __restrict__ inA,
    const float* __restrict__ w, const float* __restrict__ b,
    _Float16* __restrict__ oph, _Float16* __restrict__ opl,
    const float* __restrict__ w_u1, const float* __restrict__ w_u2,
    const float* __restrict__ w_d2, const float* __restrict__ w_bn,
    const float* __restrict__ w_p2, const float* __restrict__ w_hm,
    const float* __restrict__ w_paf,
    _Float16* __restrict__ bp_u1, _Float16* __restrict__ bp_u2,
    _Float16* __restrict__ bp_d2, _Float16* __restrict__ bp_bn,
    _Float16* __restrict__ bp_p2, _Float16* __restrict__ bp_hm,
    _Float16* __restrict__ bp_paf)
{
    const int N = 8, H = 384, W = 384, Cout = 32, Ca = 3;
    const int POOLX = 288;
    const int POOLBLKS = POOLX * 4;
    int blk = blockIdx.x;
    if (blk >= POOLBLKS) {
        int tid = (blk - POOLBLKS) * BS + threadIdx.x;
        if (tid < 13824) { packw_gen_body(w_u1, bp_u1, 192, 64, tid, 13824); return; }
        tid -= 13824;
        if (tid < 3456)  { packw_gen_body(w_u2, bp_u2, 96, 32, tid, 3456); return; }
        tid -= 3456;
        if (tid < 2304)  { packw_gen_body(w_d2, bp_d2, 32, 64, tid, 2304); return; }
        tid -= 2304;
        if (tid < 9216)  { packw_gen_body(w_bn, bp_bn, 64, 128, tid, 9216); return; }
        tid -= 9216;
        if (tid < 9216)  { packw_gen_body(w_p2, bp_p2, 64, 128, tid, 9216); return; }
        tid -= 9216;
        if (tid < 512)   { packw_1x1_body(w_hm, bp_hm, 128, 2, 17, tid, 512); return; }
        tid -= 512;
        if (tid < 512)   { packw_1x1_body(w_paf, bp_paf, 128, 2, 32, tid, 512); return; }
        return;
    }

    const int TCO = 8;
    const int W8 = W >> 3;
    const int H2 = H >> 1, W2 = W >> 1;
    int bx = blk % POOLX;
    int by = blk / POOLX;
    int idx = bx * BS + threadIdx.x;
    int total = N * H2 * W8;
    if (idx >= total) return;
    int x8 = idx % W8;
    int t  = idx / W8;
    int yo = t % H2;
    int n  = t / H2;
    int x0 = x8 << 3;
    const int co0 = by * TCO;
    const bool left_ok  = (x0 > 0);
    const bool right_ok = (x0 + 8 < W);
    const int Cin = Ca;

    float pool[TCO][4];

#pragma unroll
    for (int rr = 0; rr < 2; ++rr) {
        int y = 2 * yo + rr;
        float acc[TCO][8];
#pragma unroll
        for (int j = 0; j < TCO; ++j) {
            float bv = b[co0 + j];
#pragma unroll
            for (int p = 0; p < 8; ++p) acc[j][p] = bv;
        }

        for (int ci = 0; ci < Cin; ++ci) {
            float v[3][10];
#pragma unroll
            for (int ky = 0; ky < 3; ++ky) {
                int iy = y + ky - 1;
                if (iy < 0 || iy >= H) {
#pragma unroll
                    for (int p = 0; p < 10; ++p) v[ky][p] = 0.f;
                    continue;
                }
                const float* r = inA + ((size_t)(n * Ca + ci) * H + iy) * W;
                v[ky][0] = left_ok ? r[x0 - 1] : 0.f;
                float4 q0 = *(const float4*)(r + x0);
                float4 q1 = *(const float4*)(r + x0 + 4);
                v[ky][1] = q0.x; v[ky][2] = q0.y; v[ky][3] = q0.z; v[ky][4] = q0.w;
                v[ky][5] = q1.x; v[ky][6] = q1.y; v[ky][7] = q1.z; v[ky][8] = q1.w;
                v[ky][9] = right_ok ? r[x0 + 8] : 0.f;
            }
#pragma unroll
            for (int j = 0; j < TCO; ++j) {
                const float* wp = w + ((size_t)(co0 + j) * Cin + ci) * 9;
#pragma unroll
                for (int ky = 0; ky < 3; ++ky) {
                    float w0 = wp[ky * 3 + 0], w1 = wp[ky * 3 + 1], w2 = wp[ky * 3 + 2];
#pragma unroll
                    for (int p = 0; p < 8; ++p)
                        acc[j][p] += w0 * v[ky][p] + w1 * v[ky][p + 1] + w2 * v[ky][p + 2];
                }
            }
        }

#pragma unroll
        for (int j = 0; j < TCO; ++j) {
#pragma unroll
            for (int p4 = 0; p4 < 4; ++p4) {
                float mrow = fmaxf(fmaxf(acc[j][2 * p4], 0.f),
                                   fmaxf(acc[j][2 * p4 + 1], 0.f));
                pool[j][p4] = (rr == 0) ? mrow : fmaxf(pool[j][p4], mrow);
            }
        }
    }

#pragma unroll
    for (int p4 = 0; p4 < 4; ++p4) {
        half8 hv, lv;
#pragma unroll
        for (int j = 0; j < 8; ++j) {
            float v = pool[j][p4];
            _Float16 h = (_Float16)v;
            hv[j] = h;
            lv[j] = (_Float16)(v - (float)h);
        }
        size_t oa = ((size_t)((n * (Cout >> 3) + (co0 >> 3)) * H2 + yo) * W2
                     + (x0 >> 1) + p4) * 8;
        *(half8*)(oph + oa) = hv;
        *(half8*)(opl + oa) = lv;
    }
}

// ===========================================================================
// Generic stride-1 3x3 SAME conv via MFMA, SPLIT input: block = 2 rows x 32 px.
// OUTMODE: 1 = split only (bn).
// ===========================================================================
template <int CHUNKS, int NT, int HH, int WW, int OUTMODE>
__global__ __launch_bounds__(BS) void conv3x3s_mfma_kernel(
    const _Float16* __restrict__ inh, const _Float16* __restrict__ inl,
    const _Float16* __restrict__ bp,
    const float* __restrict__ bias,
    _Float16* __restrict__ osph,
    _Float16* __restrict__ ospl)
{
    constexpr int PL = 4 * 34 * LDSDW;
    constexpr int EPI = 64 * NT * 16;
    constexpr int LDS_DW = (2 * PL > EPI) ? 2 * PL : EPI;
    __shared__ unsigned int lds[LDS_DW];

    int xblks = WW / 32;
    int b = blockIdx.x;
    int xb = b % xblks; b /= xblks;
    int yp = b % (HH / 2);
    int n  = b / (HH / 2);
    int y0 = yp * 2;
    int x0 = xb * 32;

    int tid = threadIdx.x;
    int lane = tid & 63, wv = tid >> 6;
    int m = lane & 15, q = lane >> 4;
    int lrow = wv >> 1;
    int lx   = (wv & 1) * 16;

    floatx4 acc[NT];
#pragma unroll
    for (int nt = 0; nt < NT; ++nt) acc[nt] = (floatx4){0.f, 0.f, 0.f, 0.f};

    const int planeW = CHUNKS * 9 * NT * 64 * 8;

    for (int chunk = 0; chunk < CHUNKS; ++chunk) {
        __syncthreads();
        for (int e = tid; e < 4 * 34 * 4; e += BS) {
            int xi = e % 34;
            int rest = e / 34;
            int oct = rest & 3;
            int row = rest >> 2;
            int iy = y0 - 1 + row, gx = x0 - 1 + xi;
            half8 hv = {}, lv = {};
            if (iy >= 0 && iy < HH && gx >= 0 && gx < WW) {
                size_t ga = ((size_t)((n * (CHUNKS * 4) + chunk * 4 + oct) * HH + iy) * WW + gx) * 8;
                hv = *(const half8*)(inh + ga);
                lv = *(const half8*)(inl + ga);
            }
            int base = (row * 34 + xi) * LDSDW + oct * 4;
            *(half8*)((char*)lds + (size_t)base * 4) = hv;
            *(half8*)((char*)lds + ((size_t)PL + base) * 4) = lv;
        }
        __syncthreads();
#pragma unroll
        for (int ky = 0; ky < 3; ++ky) {
#pragma unroll
            for (int kx = 0; kx < 3; ++kx) {
                int row = lrow + ky;
                int xi  = lx + m + kx;
                int adw = (row * 34 + xi) * LDSDW + q * 4;
                half8 ah = *(const half8*)((const char*)lds + (size_t)adw * 4);
                half8 al = *(const half8*)((const char*)lds + ((size_t)PL + adw) * 4);
                int tap = ky * 3 + kx;
                const _Float16* bpp = bp + ((size_t)(chunk * 9 + tap) * NT) * 64 * 8;
#pragma unroll
                for (int nt = 0; nt < NT; ++nt) {
                    half8 bh = *(const half8*)(bpp + ((size_t)nt * 64 + lane) * 8);
                    half8 bl = *(const half8*)(bpp + planeW + ((size_t)nt * 64 + lane) * 8);
                    acc[nt] = __builtin_amdgcn_mfma_f32_16x16x32_f16(ah, bh, acc[nt], 0, 0, 0);
                    acc[nt] = __builtin_amdgcn_mfma_f32_16x16x32_f16(ah, bl, acc[nt], 0, 0, 0);
                    acc[nt] = __builtin_amdgcn_mfma_f32_16x16x32_f16(al, bh, acc[nt], 0, 0, 0);
                }
            }
        }
    }

    __syncthreads();
#pragma unroll
    for (int nt = 0; nt < NT; ++nt) {
#pragma unroll
        for (int r = 0; r < 4; ++r) {
            int co = nt * 16 + m;
            int pxl = wv * 16 + q * 4 + r;
            ((float*)lds)[co * 64 + pxl] = acc[nt][r];
        }
    }
    __syncthreads();
    {
        constexpr int OCTS = NT * 2;
        for (int it = tid; it < OCTS * 64; it += BS) {
            int px = it & 63;
            int oct = it >> 6;
            int row = y0 + (px >> 5), xx = x0 + (px & 31);
            half8 hv, lv;
#pragma unroll
            for (int j = 0; j < 8; ++j) {
                float v = fmaxf(((float*)lds)[(oct * 8 + j) * 64 + px] + bias[oct * 8 + j], 0.f);
                _Float16 hh = (_Float16)v;
                hv[j] = hh;
                lv[j] = (_Float16)(v - (float)hh);
            }
            size_t oaddr = ((size_t)((n * OCTS + oct) * HH + row) * WW + xx) * 8;
            *(half8*)(osph + oaddr) = hv;
            *(half8*)(ospl + oaddr) = lv;
        }
    }
}

// ===========================================================================
// d2 = relu(conv3x3(pd1; 32->64)) @192, 4 rows x 48 px (R24: exact rounds).
// ===========================================================================
__global__ __launch_bounds__(BS) void d2_mfma4_kernel(
    const _Float16* __restrict__ inh, const _Float16* __restrict__ inl,  // pd1sp [8,4,192,192,8]
    const _Float16* __restrict__ bp,                                     // bp_d2 (9 taps x 4nt)
    const float* __restrict__ bias,                                      // b_d2 [64]
    _Float16* __restrict__ oh, _Float16* __restrict__ ol_,               // d2sp [8,8,192,192,8]
    _Float16* __restrict__ oph, _Float16* __restrict__ opl)              // pd2sp [8,8,96,96,8]
{
    __shared__ unsigned int lds[2 * PLT4 + 128];
    const int Ho = 192, Wo = 192;
    int b = blockIdx.x;
    int xb = b % 4; b /= 4;
    int yb = b % 48;
    int n  = b / 48;
    int y0 = yb * 4;
    int x0 = xb * 48;

    int tid = threadIdx.x;
    int lane = tid & 63, wv = tid >> 6;               // wv 0..3
    int m = lane & 15, q = lane >> 4;

    floatx4 acc[3][4];
#pragma unroll
    for (int mt = 0; mt < 3; ++mt)
#pragma unroll
        for (int nt = 0; nt < 4; ++nt) acc[mt][nt] = (floatx4){0.f, 0.f, 0.f, 0.f};

    for (int e = tid; e < 6 * 50 * 4; e += BS) {
        int xi = e % 50;
        int rest = e / 50;
        int oct = rest & 3;
        int row = rest >> 2;
        int iy = y0 - 1 + row, gx = x0 - 1 + xi;
        half8 hv = {}, lv = {};
        if (iy >= 0 && iy < Ho && gx >= 0 && gx < Wo) {
            size_t ga = ((size_t)((n * 4 + oct) * Ho + iy) * Wo + gx) * 8;
            hv = *(const half8*)(inh + ga);
            lv = *(const half8*)(inl + ga);
        }
        int base = (row * 50 + xi) * LDSDW + oct * 4;
        *(half8*)((char*)lds + (size_t)base * 4) = hv;
        *(half8*)((char*)lds + ((size_t)PLT4 + base) * 4) = lv;
    }
    __syncthreads();
#pragma unroll
    for (int ky = 0; ky < 3; ++ky) {
#pragma unroll
        for (int kx = 0; kx < 3; ++kx) {
            int tap = ky * 3 + kx;
            const _Float16* bpp = bp + (size_t)tap * 2048;
            half8 bh[4], bl[4];
#pragma unroll
            for (int nt = 0; nt < 4; ++nt) {
                bh[nt] = *(const half8*)(bpp + ((size_t)nt * 64 + lane) * 8);
                bl[nt] = *(const half8*)(bpp + 18432 + ((size_t)nt * 64 + lane) * 8);
            }
            int row = wv + ky;
#pragma unroll
            for (int mt = 0; mt < 3; ++mt) {
                int px = 16 * mt + m;
                int xi = px + kx;
                int adw = (row * 50 + xi) * LDSDW + q * 4;
                half8 ah = *(const half8*)((const char*)lds + (size_t)adw * 4);
                half8 al = *(const half8*)((const char*)lds + ((size_t)PLT4 + adw) * 4);
#pragma unroll
                for (int nt = 0; nt < 4; ++nt) {
                    acc[mt][nt] = __builtin_amdgcn_mfma_f32_16x16x32_f16(ah, bh[nt], acc[mt][nt], 0, 0, 0);
                    acc[mt][nt] = __builtin_amdgcn_mfma_f32_16x16x32_f16(ah, bl[nt], acc[mt][nt], 0, 0, 0);
                    acc[mt][nt] = __builtin_amdgcn_mfma_f32_16x16x32_f16(al, bh[nt], acc[mt][nt], 0, 0, 0);
                }
            }
        }
    }

#pragma unroll
    for (int h = 0; h < 2; ++h) {
        __syncthreads();
#pragma unroll
        for (int ntl = 0; ntl < 2; ++ntl) {
#pragma unroll
            for (int mt = 0; mt < 3; ++mt) {
#pragma unroll
                for (int r = 0; r < 4; ++r) {
                    ((float*)lds)[(ntl * 16 + m) * ESTR4 + wv * 48 + 16 * mt + q * 4 + r]
                        = acc[mt][h * 2 + ntl][r];
                }
            }
        }
        __syncthreads();
        for (int it = tid; it < 4 * 192; it += BS) {
            int px = it % 192;
            int ol = it / 192;
            int row = y0 + px / 48, xx = x0 + px % 48;
            half8 hv, lv;
#pragma unroll
            for (int j = 0; j < 8; ++j) {
                int col = ol * 8 + j;
                float v = fmaxf(((float*)lds)[col * ESTR4 + px] + bias[h * 32 + col], 0.f);
                _Float16 hh = (_Float16)v;
                hv[j] = hh;
                lv[j] = (_Float16)(v - (float)hh);
            }
            size_t oaddr = ((size_t)((n * 8 + h * 4 + ol) * Ho + row) * Wo + xx) * 8;
            *(half8*)(oh + oaddr) = hv;
            *(half8*)(ol_ + oaddr) = lv;
        }
        for (int it = tid; it < 4 * 2 * 24; it += BS) {
            int xo = it % 24;
            int rest = it / 24;
            int ro = rest & 1;
            int ol = rest >> 1;
            half8 hv, lv;
#pragma unroll
            for (int j = 0; j < 8; ++j) {
                int col = ol * 8 + j;
                float bb = bias[h * 32 + col];
                const float* buf = (const float*)lds + col * ESTR4;
                float t0 = fmaxf(fmaxf(buf[(2 * ro) * 48 + 2 * xo] + bb, 0.f),
                                 fmaxf(buf[(2 * ro) * 48 + 2 * xo + 1] + bb, 0.f));
                float t1 = fmaxf(fmaxf(buf[(2 * ro + 1) * 48 + 2 * xo] + bb, 0.f),
                                 fmaxf(buf[(2 * ro + 1) * 48 + 2 * xo + 1] + bb, 0.f));
                float v = fmaxf(t0, t1);
                _Float16 hh = (_Float16)v;
                hv[j] = hh;
                lv[j] = (_Float16)(v - (float)hh);
            }
            size_t oaddr = ((size_t)((n * 8 + h * 4 + ol) * 96 + (yb * 2 + ro)) * 96
                            + (xb * 24 + xo)) * 8;
            *(half8*)(oph + oaddr) = hv;
            *(half8*)(opl + oaddr) = lv;
        }
    }
}

// ===========================================================================
// Stride-2 3x3 conv via MFMA, SPLIT input + SPLIT output (p2).
// R27: LDS stride 68 -> 66 (52,800 B staged -> 3 blocks/CU). Reads only ever
// touch pos {0..32}u{34..65}; stores guarded pos < 66 (skips unread zeros).
// ===========================================================================
template <int CHUNKS, int NT, int WI>
__global__ __launch_bounds__(BS) void conv3x3s2s_mfma_kernel(
    const _Float16* __restrict__ inh, const _Float16* __restrict__ inl,
    const _Float16* __restrict__ bp,
    const float* __restrict__ bias,  // [NT*16]
    _Float16* __restrict__ oh, _Float16* __restrict__ ol_)  // [8, NT*2, WO, WO, 8]
{
    constexpr int WO = WI / 2;
    constexpr int PLs = 5 * 66 * LDSDW;               // 6600 dw per plane
    constexpr int EPI = 64 * NT * 16;
    constexpr int LDS_DW = (2 * PLs > EPI) ? 2 * PLs : EPI;
    __shared__ unsigned int lds[LDS_DW];

    int xblks = WO / 32;
    int b = blockIdx.x;
    int xb = b % xblks; b /= xblks;
    int yp = b % (WO / 2);
    int n  = b / (WO / 2);
    int y0 = yp * 2;
    int x0 = xb * 32;

    int tid = threadIdx.x;
    int lane = tid & 63, wv = tid >> 6;
    int m = lane & 15, q = lane >> 4;
    int lrow = wv >> 1;
    int lx   = (wv & 1) * 16;

    floatx4 acc[NT];
#pragma unroll
    for (int nt = 0; nt < NT; ++nt) acc[nt] = (floatx4){0.f, 0.f, 0.f, 0.f};

    const int planeW = CHUNKS * 9 * NT * 64 * 8;

    for (int chunk = 0; chunk < CHUNKS; ++chunk) {
        __syncthreads();
        for (int e = tid; e < 5 * 68 * 4; e += BS) {
            int xi = e % 68;
            int rest = e / 68;
            int oct = rest & 3;
            int row = rest >> 2;
            int iy = 2 * y0 + row, ix = 2 * x0 + xi;
            half8 hv = {}, lv = {};
            if (xi < 65 && iy < WI && ix < WI) {
                size_t ga = ((size_t)((n * (CHUNKS * 4) + chunk * 4 + oct) * WI + iy) * WI + ix) * 8;
                hv = *(const half8*)(inh + ga);
                lv = *(const half8*)(inl + ga);
            }
            int pos = (xi & 1) * 34 + (xi >> 1);
            if (pos < 66) {                            // pos 66/67 never read
                int base = (row * 66 + pos) * LDSDW + oct * 4;
                *(half8*)((char*)lds + (size_t)base * 4) = hv;
                *(half8*)((char*)lds + ((size_t)PLs + base) * 4) = lv;
            }
        }
        __syncthreads();
#pragma unroll
        for (int ky = 0; ky < 3; ++ky) {
#pragma unroll
            for (int kx = 0; kx < 3; ++kx) {
                int row = 2 * lrow + ky;
                int pos = (kx & 1) * 34 + (lx + m) + (kx >> 1);
                int adw = (row * 66 + pos) * LDSDW + q * 4;
                half8 ah = *(const half8*)((const char*)lds + (size_t)adw * 4);
                half8 al = *(const half8*)((const char*)lds + ((size_t)PLs + adw) * 4);
                int tap = ky * 3 + kx;
                const _Float16* bpp = bp + ((size_t)(chunk * 9 + tap) * NT) * 64 * 8;
#pragma unroll
                for (int nt = 0; nt < NT; ++nt) {
                    half8 bh = *(const half8*)(bpp + ((size_t)nt * 64 + lane) * 8);
                    half8 bl = *(const half8*)(bpp + planeW + ((size_t)nt * 64 + lane) * 8);
                    acc[nt] = __builtin_amdgcn_mfma_f32_16x16x32_f16(ah, bh, acc[nt], 0, 0, 0);
                    acc[nt] = __builtin_amdgcn_mfma_f32_16x16x32_f16(ah, bl, acc[nt], 0, 0, 0);
                    acc[nt] = __builtin_amdgcn_mfma_f32_16x16x32_f16(al, bh, acc[nt], 0, 0, 0);
                }
            }
        }
    }

    __syncthreads();
#pragma unroll
    for (int nt = 0; nt < NT; ++nt) {
#pragma unroll
        for (int r = 0; r < 4; ++r) {
            int co = nt * 16 + m;
            int pxl = wv * 16 + q * 4 + r;
            ((float*)lds)[co * 64 + pxl] = acc[nt][r];
        }
    }
    __syncthreads();
    {
        constexpr int OCTS = NT * 2;
        for (int it = tid; it < OCTS * 64; it += BS) {
            int px = it & 63;
            int oct = it >> 6;
            int row = y0 + (px >> 5), xx = x0 + (px & 31);
            half8 hv, lv;
#pragma unroll
            for (int j = 0; j < 8; ++j) {
                float v = fmaxf(((float*)lds)[(oct * 8 + j) * 64 + px] + bias[oct * 8 + j], 0.f);
                _Float16 hh = (_Float16)v;
                hv[j] = hh;
                lv[j] = (_Float16)(v - (float)hh);
            }
            size_t oaddr = ((size_t)((n * OCTS + oct) * WO + row) * WO + xx) * 8;
            *(half8*)(oh + oaddr) = hv;
            *(half8*)(ol_ + oaddr) = lv;
        }
    }
}

// ===========================================================================
// Merged heads: hm (17) + paf (32) 1x1 convs over p2sp, one staging pass. (R24)
// ===========================================================================
__global__ __launch_bounds__(BS) void conv1x1_heads_kernel(
    const _Float16* __restrict__ inh, const _Float16* __restrict__ inl,  // [8,16,HW,8]
    const _Float16* __restrict__ bph, const _Float16* __restrict__ bpp,  // bp_hm, bp_paf
    const float* __restrict__ bh_, const float* __restrict__ bpf,        // b_hm, b_paf
    float* __restrict__ out_hm, float* __restrict__ out_paf, int HW)
{
    constexpr int PL1 = 64 * LDSDW;                   // 1280 dw
    __shared__ unsigned int lds[64 * 64];

    int pblks = HW / 64;
    int b = blockIdx.x;
    int pb = b % pblks;
    int n  = b / pblks;
    int sp0 = pb * 64;

    int tid = threadIdx.x;
    int lane = tid & 63, wv = tid >> 6;
    int m = lane & 15, q = lane >> 4;

    floatx4 acc[4];
#pragma unroll
    for (int nt = 0; nt < 4; ++nt) acc[nt] = (floatx4){0.f, 0.f, 0.f, 0.f};

    for (int chunk = 0; chunk < 4; ++chunk) {
        __syncthreads();
        {
            int px = tid & 63;
            int oct = tid >> 6;
            size_t ga = (((size_t)(n * 16 + chunk * 4 + oct)) * HW + sp0 + px) * 8;
            half8 hv = *(const half8*)(inh + ga);
            half8 lv = *(const half8*)(inl + ga);
            int base = px * LDSDW + oct * 4;
            *(half8*)((char*)lds + (size_t)base * 4) = hv;
            *(half8*)((char*)lds + ((size_t)PL1 + base) * 4) = lv;
        }
        __syncthreads();
        {
            int adw = (wv * 16 + m) * LDSDW + q * 4;
            half8 ah = *(const half8*)((const char*)lds + (size_t)adw * 4);
            half8 al = *(const half8*)((const char*)lds + ((size_t)PL1 + adw) * 4);
#pragma unroll
            for (int nt = 0; nt < 4; ++nt) {
                const _Float16* base = (nt < 2) ? bph : bpp;
                int ntl = nt & 1;
                const _Float16* pbh = base + (size_t)(chunk * 2 + ntl) * 512 + (size_t)lane * 8;
                half8 bh = *(const half8*)pbh;
                half8 bl = *(const half8*)(pbh + 4096);
                acc[nt] = __builtin_amdgcn_mfma_f32_16x16x32_f16(ah, bh, acc[nt], 0, 0, 0);
                acc[nt] = __builtin_amdgcn_mfma_f32_16x16x32_f16(ah, bl, acc[nt], 0, 0, 0);
                acc[nt] = __builtin_amdgcn_mfma_f32_16x16x32_f16(al, bh, acc[nt], 0, 0, 0);
            }
        }
    }

    __syncthreads();
#pragma unroll
    for (int nt = 0; nt < 4; ++nt) {
#pragma unroll
        for (int r = 0; r < 4; ++r) {
            ((float*)lds)[(nt * 16 + m) * 64 + wv * 16 + q * 4 + r] = acc[nt][r];
        }
    }
    __syncthreads();
    {
        int co = tid >> 2;
        int g  = tid & 3;
        const float* lp = (const float*)lds + co * 64 + g * 16;
        if (co < 17) {
            float bb = bh_[co];
            float* op = out_hm + ((size_t)(n * 17 + co)) * HW + sp0 + g * 16;
#pragma unroll
            for (int u = 0; u < 16; u += 4) {
                float4 vv = *(const float4*)(lp + u);
                vv.x += bb; vv.y += bb; vv.z += bb; vv.w += bb;
                *(float4*)(op + u) = vv;
            }
        } else if (co >= 32) {
            int pco = co - 32;
            float bb = bpf[pco];
            float* op = out_paf + ((size_t)(n * 32 + pco)) * HW + sp0 + g * 16;
#pragma unroll
            for (int u = 0; u < 16; u += 4) {
                float4 vv = *(const float4*)(lp + u);
                vv.x += bb; vv.y += bb; vv.z += bb; vv.w += bb;
                *(float4*)(op + u) = vv;
            }
        }
    }
}

// ===========================================================================
// u1 = relu(conv3x3(concat(up2(bn), d2))) via MFMA, 4 rows x 48 px @192. (R23)
// ===========================================================================
__global__ __launch_bounds__(BS) void u1_mfma_kernel(
    const _Float16* __restrict__ bnh, const _Float16* __restrict__ bnl,  // [8,16,96,96,8]
    const _Float16* __restrict__ d2h, const _Float16* __restrict__ d2l,  // [8,8,192,192,8]
    const _Float16* __restrict__ bp,
    const float* __restrict__ b_u1,  // [64]
    _Float16* __restrict__ oh, _Float16* __restrict__ ol_)               // [8,8,192,192,8]
{
    __shared__ unsigned int lds[2 * PLT4 + 128];
    const int Ho = 192, Wo = 192;
    int b = blockIdx.x;
    int xb = b % 4; b /= 4;
    int yb = b % 48;
    int n  = b / 48;
    int y0 = yb * 4;
    int x0 = xb * 48;

    int tid = threadIdx.x;
    int lane = tid & 63, wv = tid >> 6;               // wv 0..3
    int m = lane & 15, q = lane >> 4;
    int yr = y0 + wv;

    floatx4 acc[3][4];
#pragma unroll
    for (int mt = 0; mt < 3; ++mt)
#pragma unroll
        for (int nt = 0; nt < 4; ++nt) acc[mt][nt] = (floatx4){0.f, 0.f, 0.f, 0.f};

    const int hh0 = (y0 - 1) >> 1;
    const int hx0 = (x0 - 1) >> 1;

    for (int chunk = 0; chunk < 6; ++chunk) {
        __syncthreads();
        if (chunk < 4) {
            for (int e = tid; e < 4 * 26 * 4; e += BS) {
                int xi = e % 26;
                int rest = e / 26;
                int oct = rest & 3;
                int row = rest >> 2;
                int hy = hh0 + row, hx = hx0 + xi;
                half8 hv = {}, lv = {};
                if (hy >= 0 && hy < 96 && hx >= 0 && hx < 96) {
                    size_t ga = ((size_t)((n * 16 + chunk * 4 + oct) * 96 + hy) * 96 + hx) * 8;
                    hv = *(const half8*)(bnh + ga);
                    lv = *(const half8*)(bnl + ga);
                }
                int base = (row * 50 + xi) * LDSDW + oct * 4;
                *(half8*)((char*)lds + (size_t)base * 4) = hv;
                *(half8*)((char*)lds + ((size_t)PLT4 + base) * 4) = lv;
            }
        } else {
            for (int e = tid; e < 6 * 50 * 4; e += BS) {
                int xi = e % 50;
                int rest = e / 50;
                int oct = rest & 3;
                int row = rest >> 2;
                int iy = y0 - 1 + row, gx = x0 - 1 + xi;
                half8 hv = {}, lv = {};
                if (iy >= 0 && iy < Ho && gx >= 0 && gx < Wo) {
                    size_t ga = ((size_t)((n * 8 + (chunk - 4) * 4 + oct) * Ho + iy) * Wo + gx) * 8;
                    hv = *(const half8*)(d2h + ga);
                    lv = *(const half8*)(d2l + ga);
                }
                int base = (row * 50 + xi) * LDSDW + oct * 4;
                *(half8*)((char*)lds + (size_t)base * 4) = hv;
                *(half8*)((char*)lds + ((size_t)PLT4 + base) * 4) = lv;
            }
        }
        __syncthreads();
#pragma unroll
        for (int ky = 0; ky < 3; ++ky) {
#pragma unroll
            for (int kx = 0; kx < 3; ++kx) {
                int tap = ky * 3 + kx;
                const _Float16* bpp = bp + ((size_t)(chunk * 9 + tap) * 4) * 64 * 8;
                half8 bh[4], bl[4];
#pragma unroll
                for (int nt = 0; nt < 4; ++nt) {
                    bh[nt] = *(const half8*)(bpp + ((size_t)nt * 64 + lane) * 8);
                    bl[nt] = *(const half8*)(bpp + 110592 + ((size_t)nt * 64 + lane) * 8);
                }
                int row;
                if (chunk < 4) row = ((yr + ky - 1) >> 1) - hh0;
                else           row = wv + ky;
#pragma unroll
                for (int mt = 0; mt < 3; ++mt) {
                    int px = 16 * mt + m;
                    int xi = (chunk < 4) ? (((x0 + px + kx - 1) >> 1) - hx0)
                                         : (px + kx);
                    int adw = (row * 50 + xi) * LDSDW + q * 4;
                    half8 ah = *(const half8*)((const char*)lds + (size_t)adw * 4);
                    half8 al = *(const half8*)((const char*)lds + ((size_t)PLT4 + adw) * 4);
#pragma unroll
                    for (int nt = 0; nt < 4; ++nt) {
                        acc[mt][nt] = __builtin_amdgcn_mfma_f32_16x16x32_f16(ah, bh[nt], acc[mt][nt], 0, 0, 0);
                        acc[mt][nt] = __builtin_amdgcn_mfma_f32_16x16x32_f16(ah, bl[nt], acc[mt][nt], 0, 0, 0);
                        acc[mt][nt] = __builtin_amdgcn_mfma_f32_16x16x32_f16(al, bh[nt], acc[mt][nt], 0, 0, 0);
                    }
                }
            }
        }
    }

    // epilogue: 2 halves of 32 co; buffer [32 co][stride ESTR4; 192 px used]
#pragma unroll
    for (int h = 0; h < 2; ++h) {
        __syncthreads();
#pragma unroll
        for (int ntl = 0; ntl < 2; ++ntl) {
#pragma unroll
            for (int mt = 0; mt < 3; ++mt) {
#pragma unroll
                for (int r = 0; r < 4; ++r) {
                    ((float*)lds)[(ntl * 16 + m) * ESTR4 + wv * 48 + 16 * mt + q * 4 + r]
                        = acc[mt][h * 2 + ntl][r];
                }
            }
        }
        __syncthreads();
        for (int it = tid; it < 4 * 192; it += BS) {
            int px = it % 192;
            int ol = it / 192;
            int row = y0 + px / 48, xx = x0 + px % 48;
            half8 hv, lv;
#pragma unroll
            for (int j = 0; j < 8; ++j) {
                int col = ol * 8 + j;
                float v = fmaxf(((float*)lds)[col * ESTR4 + px] + b_u1[h * 32 + col], 0.f);
                _Float16 hh = (_Float16)v;
                hv[j] = hh;
                lv[j] = (_Float16)(v - (float)hh);
            }
            size_t oaddr = ((size_t)((n * 8 + h * 4 + ol) * Ho + row) * Wo + xx) * 8;
            *(half8*)(oh + oaddr) = hv;
            *(half8*)(ol_ + oaddr) = lv;
        }
    }
}

// ===========================================================================
// seg via fused MFMA u2+seg, 8 rows x 48 px @384; shfl_xor co-reduce. (R18)
// ===========================================================================
__global__ __launch_bounds__(BSW) void u2seg_mfma_kernel(
    const _Float16* __restrict__ u1h, const _Float16* __restrict__ u1l,  // [8,8,192,192,8]
    const _Float16* __restrict__ d1h, const _Float16* __restrict__ d1l,  // [8,4,384,384,8]
    const _Float16* __restrict__ bp,
    const float* __restrict__ b_u2,  // [32]
    const float* __restrict__ w_seg, // [32]
    const float* __restrict__ b_seg, // [1]
    float* __restrict__ seg)         // [8,1,384,384]
{
    __shared__ unsigned int lds[2 * PLT8];
    const int Ho = 384, Wo = 384;
    int b = blockIdx.x;
    int xb = b % 8; b /= 8;
    int yb = b % 48;
    int n  = b / 48;
    int y0 = yb * 8;
    int x0 = xb * 48;

    int tid = threadIdx.x;
    int lane = tid & 63, wv = tid >> 6;
    int m = lane & 15, q = lane >> 4;
    int yr = y0 + wv;

    floatx4 acc[3][2];
#pragma unroll
    for (int mt = 0; mt < 3; ++mt) {
        acc[mt][0] = (floatx4){0.f, 0.f, 0.f, 0.f};
        acc[mt][1] = (floatx4){0.f, 0.f, 0.f, 0.f};
    }

    const int hh0 = (y0 - 1) >> 1;
    const int hx0 = (x0 - 1) >> 1;

    for (int chunk = 0; chunk < 3; ++chunk) {
        __syncthreads();
        if (chunk < 2) {
            for (int e = tid; e < 6 * 26 * 4; e += BSW) {
                int xi = e % 26;
                int rest = e / 26;
                int oct = rest & 3;
                int row = rest >> 2;
                int hy = hh0 + row, hx = hx0 + xi;
                half8 hv = {}, lv = {};
                if (hy >= 0 && hy < 192 && hx >= 0 && hx < 192) {
                    size_t ga = ((size_t)((n * 8 + chunk * 4 + oct) * 192 + hy) * 192 + hx) * 8;
                    hv = *(const half8*)(u1h + ga);
                    lv = *(const half8*)(u1l + ga);
                }
                int base = (row * 50 + xi) * LDSDW + oct * 4;
                *(half8*)((char*)lds + (size_t)base * 4) = hv;
                *(half8*)((char*)lds + ((size_t)PLT8 + base) * 4) = lv;
            }
        } else {
            for (int e = tid; e < 10 * 50 * 4; e += BSW) {
                int xi = e % 50;
                int rest = e / 50;
                int oct = rest & 3;
                int row = rest >> 2;
                int iy = y0 - 1 + row, gx = x0 - 1 + xi;
                half8 hv = {}, lv = {};
                if (iy >= 0 && iy < Ho && gx >= 0 && gx < Wo) {
                    size_t ga = ((size_t)((n * 4 + oct) * Ho + iy) * Wo + gx) * 8;
                    hv = *(const half8*)(d1h + ga);
                    lv = *(const half8*)(d1l + ga);
                }
                int base = (row * 50 + xi) * LDSDW + oct * 4;
                *(half8*)((char*)lds + (size_t)base * 4) = hv;
                *(half8*)((char*)lds + ((size_t)PLT8 + base) * 4) = lv;
            }
        }
        __syncthreads();
#pragma unroll
        for (int ky = 0; ky < 3; ++ky) {
#pragma unroll
            for (int kx = 0; kx < 3; ++kx) {
                int tap = ky * 3 + kx;
                const _Float16* bpp = bp + ((size_t)(chunk * 9 + tap) * 2) * 64 * 8;
                half8 bh0 = *(const half8*)(bpp + (size_t)lane * 8);
                half8 bl0 = *(const half8*)(bpp + 27648 + (size_t)lane * 8);
                half8 bh1 = *(const half8*)(bpp + ((size_t)64 + lane) * 8);
                half8 bl1 = *(const half8*)(bpp + 27648 + ((size_t)64 + lane) * 8);
                int row;
                if (chunk < 2) row = ((yr + ky - 1) >> 1) - hh0;
                else           row = wv + ky;
#pragma unroll
                for (int mt = 0; mt < 3; ++mt) {
                    int px = 16 * mt + m;
                    int xi = (chunk < 2) ? (((x0 + px + kx - 1) >> 1) - hx0)
                                         : (px + kx);
                    int adw = (row * 50 + xi) * LDSDW + q * 4;
                    half8 ah = *(const half8*)((const char*)lds + (size_t)adw * 4);
                    half8 al = *(const half8*)((const char*)lds + ((size_t)PLT8 + adw) * 4);
                    acc[mt][0] = __builtin_amdgcn_mfma_f32_16x16x32_f16(ah, bh0, acc[mt][0], 0, 0, 0);
                    acc[mt][0] = __builtin_amdgcn_mfma_f32_16x16x32_f16(ah, bl0, acc[mt][0], 0, 0, 0);
                    acc[mt][0] = __builtin_amdgcn_mfma_f32_16x16x32_f16(al, bh0, acc[mt][0], 0, 0, 0);
                    acc[mt][1] = __builtin_amdgcn_mfma_f32_16x16x32_f16(ah, bh1, acc[mt][1], 0, 0, 0);
                    acc[mt][1] = __builtin_amdgcn_mfma_f32_16x16x32_f16(ah, bl1, acc[mt][1], 0, 0, 0);
                    acc[mt][1] = __builtin_amdgcn_mfma_f32_16x16x32_f16(al, bh1, acc[mt][1], 0, 0, 0);
                }
            }
        }
    }

    float bb0 = b_u2[m], bb1 = b_u2[16 + m];
    float ws0 = w_seg[m], ws1 = w_seg[16 + m];
    float bseg = b_seg[0];
#pragma unroll
    for (int mt = 0; mt < 3; ++mt) {
        float sr[4];
#pragma unroll
        for (int r = 0; r < 4; ++r) {
            float p = ws0 * fmaxf(acc[mt][0][r] + bb0, 0.f)
                    + ws1 * fmaxf(acc[mt][1][r] + bb1, 0.f);
            p += __shfl_xor(p, 1);
            p += __shfl_xor(p, 2);
            p += __shfl_xor(p, 4);
            p += __shfl_xor(p, 8);
            sr[r] = p + bseg;
        }
        if (m == 0) {
            float4 o; o.x = sr[0]; o.y = sr[1]; o.z = sr[2]; o.w = sr[3];
            *(float4*)(seg + ((size_t)n * Ho + yr) * Wo + x0 + 16 * mt + q * 4) = o;
        }
    }
}

// ===========================================================================
// Vector kernels.
// ===========================================================================

template <int UPA, int TCO, int SPLIT>
__global__ __launch_bounds__(BS, 2) void conv3x3_x8_kernel(
    const float* __restrict__ inA, int Ca,
    const float* __restrict__ inB, int Cb,
    const float* __restrict__ w, const float* __restrict__ b,
    float* __restrict__ out,
    int N, int H, int W, int Cout, int do_relu,
    _Float16* __restrict__ osph, _Float16* __restrict__ ospl)
{
    const int W8 = W >> 3;
    int idx = blockIdx.x * BS + threadIdx.x;
    int total = N * H * W8;
    if (idx >= total) return;
    int x8 = idx % W8;
    int t  = idx / W8;
    int y  = t % H;
    int n  = t / H;
    int x0 = x8 << 3;
    const int co0 = blockIdx.y * TCO;
    const bool left_ok  = (x0 > 0);
    const bool right_ok = (x0 + 8 < W);
    const int Cin = Ca + Cb;

    float acc[TCO][8];
#pragma unroll
    for (int j = 0; j < TCO; ++j) {
        float bv = b[co0 + j];
#pragma unroll
        for (int p = 0; p < 8; ++p) acc[j][p] = bv;
    }

    for (int ci = 0; ci < Cin; ++ci) {
        float v[3][10];
#pragma unroll
        for (int ky = 0; ky < 3; ++ky) {
            int iy = y + ky - 1;
            if (iy < 0 || iy >= H) {
#pragma unroll
                for (int p = 0; p < 10; ++p) v[ky][p] = 0.f;
                continue;
            }
            if (UPA == 2 && ci < Ca) {
                const float* r = inA + ((size_t)(n * Ca + ci) * (H >> 1) + (iy >> 1)) * (W >> 1);
                int xh = x0 >> 1;
                float sm = left_ok  ? r[xh - 1] : 0.f;
                float4 qq = *(const float4*)(r + xh);
                float s4 = right_ok ? r[xh + 4] : 0.f;
                v[ky][0] = sm;
                v[ky][1] = qq.x; v[ky][2] = qq.x;
                v[ky][3] = qq.y; v[ky][4] = qq.y;
                v[ky][5] = qq.z; v[ky][6] = qq.z;
                v[ky][7] = qq.w; v[ky][8] = qq.w;
                v[ky][9] = s4;
            } else {
                const float* r = (ci < Ca)
                    ? inA + ((size_t)(n * Ca + ci) * H + iy) * W
                    : inB + ((size_t)(n * Cb + (ci - Ca)) * H + iy) * W;
                v[ky][0] = left_ok ? r[x0 - 1] : 0.f;
                float4 q0 = *(const float4*)(r + x0);
                float4 q1 = *(const float4*)(r + x0 + 4);
                v[ky][1] = q0.x; v[ky][2] = q0.y; v[ky][3] = q0.z; v[ky][4] = q0.w;
                v[ky][5] = q1.x; v[ky][6] = q1.y; v[ky][7] = q1.z; v[ky][8] = q1.w;
                v[ky][9] = right_ok ? r[x0 + 8] : 0.f;
            }
        }
#pragma unroll
        for (int j = 0; j < TCO; ++j) {
            const float* wp = w + ((size_t)(co0 + j) * Cin + ci) * 9;
#pragma unroll
            for (int ky = 0; ky < 3; ++ky) {
                float w0 = wp[ky * 3 + 0], w1 = wp[ky * 3 + 1], w2 = wp[ky * 3 + 2];
#pragma unroll
                for (int p = 0; p < 8; ++p)
                    acc[j][p] += w0 * v[ky][p] + w1 * v[ky][p + 1] + w2 * v[ky][p + 2];
            }
        }
    }

    if (SPLIT) {
#pragma unroll
        for (int oo = 0; oo < TCO / 8; ++oo) {
#pragma unroll
            for (int p = 0; p < 8; ++p) {
                half8 hv, lv;
#pragma unroll
                for (int j = 0; j < 8; ++j) {
                    float v = acc[oo * 8 + j][p];
                    if (do_relu) v = fmaxf(v, 0.f);
                    _Float16 hh = (_Float16)v;
                    hv[j] = hh;
                    lv[j] = (_Float16)(v - (float)hh);
                }
                size_t oaddr = ((size_t)((n * (Cout >> 3) + (co0 >> 3) + oo) * H + y) * W + x0 + p) * 8;
                *(half8*)(osph + oaddr) = hv;
                *(half8*)(ospl + oaddr) = lv;
            }
        }
    } else {
#pragma unroll
        for (int j = 0; j < TCO; ++j) {
#pragma unroll
            for (int p = 0; p < 8; ++p)
                if (do_relu) acc[j][p] = fmaxf(acc[j][p], 0.f);
            float* o = out + ((size_t)(n * Cout + co0 + j) * H + y) * W + x0;
            float4 q0; q0.x = acc[j][0]; q0.y = acc[j][1]; q0.z = acc[j][2]; q0.w = acc[j][3];
            float4 q1; q1.x = acc[j][4]; q1.y = acc[j][5]; q1.z = acc[j][6]; q1.w = acc[j][7];
            *(float4*)o = q0;
            *(float4*)(o + 4) = q1;
        }
    }
}

// p1: stride-2 vector conv with SPLIT output; TCO=16 (R26).
template <int TCO, int SPLIT>
__global__ __launch_bounds__(BS) void conv3x3_s2_co_kernel(
    const float* __restrict__ inA, int Ca,
    const float* __restrict__ inB, int Cb,
    const float* __restrict__ w, const float* __restrict__ b,
    float* __restrict__ out,
    int N, int Hi, int Wi, int Cout, int do_relu,
    _Float16* __restrict__ osph, _Float16* __restrict__ ospl)
{
    const int Ho = Hi >> 1, Wo = Wi >> 1, Woq = Wo >> 2;
    int idx = blockIdx.x * BS + threadIdx.x;
    int total = N * Ho * Woq;
    if (idx >= total) return;
    int q  = idx % Woq;
    int t  = idx / Woq;
    int oy = t % Ho;
    int n  = t / Ho;
    int ox0 = q << 2;
    int ix0 = ox0 << 1;
    const int co0 = blockIdx.y * TCO;
    const bool right_ok = (ix0 + 8 < Wi);
    const int Cin = Ca + Cb;

    float acc[TCO][4];
#pragma unroll
    for (int j = 0; j < TCO; ++j) {
        float bv = b[co0 + j];
        acc[j][0] = bv; acc[j][1] = bv; acc[j][2] = bv; acc[j][3] = bv;
    }

    for (int ci = 0; ci < Cin; ++ci) {
        const float* base = (ci < Ca)
            ? inA + (size_t)(n * Ca + ci) * Hi * Wi
            : inB + (size_t)(n * Cb + (ci - Ca)) * Hi * Wi;
        float v[3][9];
#pragma unroll
        for (int ky = 0; ky < 3; ++ky) {
            int iy = 2 * oy + ky;
            if (iy >= Hi) {
#pragma unroll
                for (int p = 0; p < 9; ++p) v[ky][p] = 0.f;
                continue;
            }
            const float* r = base + (size_t)iy * Wi + ix0;
            float4 a = *(const float4*)r;
            float4 c = *(const float4*)(r + 4);
            v[ky][0] = a.x; v[ky][1] = a.y; v[ky][2] = a.z; v[ky][3] = a.w;
            v[ky][4] = c.x; v[ky][5] = c.y; v[ky][6] = c.z; v[ky][7] = c.w;
            v[ky][8] = right_ok ? r[8] : 0.f;
        }
#pragma unroll
        for (int j = 0; j < TCO; ++j) {
            const float* wp = w + ((size_t)(co0 + j) * Cin + ci) * 9;
#pragma unroll
            for (int ky = 0; ky < 3; ++ky) {
                float w0 = wp[ky * 3 + 0], w1 = wp[ky * 3 + 1], w2 = wp[ky * 3 + 2];
#pragma unroll
                for (int p = 0; p < 4; ++p)
                    acc[j][p] += w0 * v[ky][2 * p] + w1 * v[ky][2 * p + 1] + w2 * v[ky][2 * p + 2];
            }
        }
    }

    if (SPLIT) {
#pragma unroll
        for (int oo = 0; oo < TCO / 8; ++oo) {
#pragma unroll
            for (int p = 0; p < 4; ++p) {
                half8 hv, lv;
#pragma unroll
                for (int j = 0; j < 8; ++j) {
                    float v = acc[oo * 8 + j][p];
                    if (do_relu) v = fmaxf(v, 0.f);
                    _Float16 hh = (_Float16)v;
                    hv[j] = hh;
                    lv[j] = (_Float16)(v - (float)hh);
                }
                size_t oaddr = ((size_t)((n * (Cout >> 3) + (co0 >> 3) + oo) * Ho + oy) * Wo + ox0 + p) * 8;
                *(half8*)(osph + oaddr) = hv;
                *(half8*)(ospl + oaddr) = lv;
            }
        }
    } else {
#pragma unroll
        for (int j = 0; j < TCO; ++j) {
            float4 o;
            o.x = acc[j][0]; o.y = acc[j][1]; o.z = acc[j][2]; o.w = acc[j][3];
            if (do_relu) {
                o.x = fmaxf(o.x, 0.f); o.y = fmaxf(o.y, 0.f);
                o.z = fmaxf(o.z, 0.f); o.w = fmaxf(o.w, 0.f);
            }
            *(float4*)(out + ((size_t)(n * Cout + co0 + j) * Ho + oy) * Wo + ox0) = o;
        }
    }
}

__global__ __launch_bounds__(BS) void peaks_kernel(
    const float* __restrict__ hm, float* __restrict__ out,
    int NC, int H, int W, float thresh)
{
    int idx = blockIdx.x * BS + threadIdx.x;
    int total = NC * H * W;
    if (idx >= total) return;
    int x = idx % W;
    int t = idx / W;
    int y = t % H;
    int c = t / H;
    float r = 0.f;
    if (x >= 1 && x < W - 1 && y >= 1 && y < H - 1) {
        const float* base = hm + (size_t)c * H * W;
        float cv = base[y * W + x];
        if (cv > thresh &&
            cv >= base[(y - 1) * W + x] &&
            cv >= base[(y + 1) * W + x] &&
            cv >= base[y * W + (x - 1)] &&
            cv >= base[y * W + (x + 1)])
            r = 1.f;
    }
    out[idx] = r;
}

static inline int nblk(long n) { return (int)((n + BS - 1) / BS); }

extern "C" void kernel_launch(void* const* d_in, const int* in_sizes, int n_in,
                              void* d_out, int out_size, void* d_ws, size_t ws_size,
                              hipStream_t stream)
{
    const float* x     = (const float*)d_in[0];
    const float* w_d1  = (const float*)d_in[1];  const float* b_d1  = (const float*)d_in[2];
    const float* w_d2  = (const float*)d_in[3];  const float* b_d2  = (const float*)d_in[4];
    const float* w_bn  = (const float*)d_in[5];  const float* b_bn  = (const float*)d_in[6];
    const float* w_u1  = (const float*)d_in[7];  const float* b_u1  = (const float*)d_in[8];
    const float* w_u2  = (const float*)d_in[9];  const float* b_u2  = (const float*)d_in[10];
    const float* w_seg = (const float*)d_in[11]; const float* b_seg = (const float*)d_in[12];
    const float* w_p1  = (const float*)d_in[13]; const float* b_p1  = (const float*)d_in[14];
    const float* w_p2  = (const float*)d_in[15]; const float* b_p2  = (const float*)d_in[16];
    const float* w_hm  = (const float*)d_in[17]; const float* b_hm  = (const float*)d_in[18];
    const float* w_paf = (const float*)d_in[19]; const float* b_paf = (const float*)d_in[20];

    const int N = 8, H = 384, W = 384;
    const int H2 = 192, W2 = 192, H4 = 96, W4 = 96;

    float* ws = (float*)d_ws;
    // Lifetime map in header comment.
    _Float16* pd1sp_h = (_Float16*)(ws);               // s1->s3
    _Float16* pd1sp_l = (_Float16*)(ws + 4718592);
    _Float16* d2sp_h = (_Float16*)(ws + 28311552);     // s3->s6
    _Float16* d2sp_l = (_Float16*)(ws + 37748736);
    _Float16* pd2sp_h = (_Float16*)(ws + 47185920);    // s3->s5
    _Float16* pd2sp_l = (_Float16*)(ws + 49545216);
    _Float16* bnsp_h = (_Float16*)(ws + 18874368);     // s5->s6
    _Float16* bnsp_l = (_Float16*)(ws + 23592960);
    _Float16* u1sp_h = (_Float16*)(ws);                // s6->s8
    _Float16* u1sp_l = (_Float16*)(ws + 9437184);
    _Float16* d1sp_h = (_Float16*)(ws + 18874368);     // s7->s8
    _Float16* d1sp_l = (_Float16*)(ws + 37748736);
    _Float16* p1sp_h = (_Float16*)(ws);                // s9->s10
    _Float16* p1sp_l = (_Float16*)(ws + 9437184);
    _Float16* p2sp_h = (_Float16*)(ws + 18874368);     // s10->s12
    _Float16* p2sp_l = (_Float16*)(ws + 23592960);

    float* out_seg   = (float*)d_out;                 // 1179648
    float* out_hm    = out_seg + 1179648;             // 1253376
    float* out_paf   = out_hm + 1253376;              // 2359296
    float* out_peaks = out_paf + 2359296;             // 1253376
    // packed weights in the peaks region [4792320, 6045696), all consumed
    // before step 13 overwrites them. 16B-aligned. (R18 layout)
    _Float16* bp_u1  = (_Float16*)(out_seg + 4792320); // 110592 fl
    _Float16* bp_u2  = (_Float16*)(out_seg + 4902912); // 27648 fl
    _Float16* bp_d2  = (_Float16*)(out_seg + 4930560); // 18432 fl
    _Float16* bp_bn  = (_Float16*)(out_seg + 4948992); // 73728 fl
    _Float16* bp_p2  = (_Float16*)(out_seg + 5022720); // 73728 fl
    _Float16* bp_hm  = (_Float16*)(out_seg + 5096448); // 4096 fl
    _Float16* bp_paf = (_Float16*)(out_seg + 5100544); // 4096 fl -> ends 5104640

    // 0+1. pool (d1 conv+relu+maxpool -> pd1sp) + all weight packs, one launch
    pool_packw_kernel<<<1152 + 153, BS, 0, stream>>>(
        x, w_d1, b_d1, pd1sp_h, pd1sp_l,
        w_u1, w_u2, w_d2, w_bn, w_p2, w_hm, w_paf,
        bp_u1, bp_u2, bp_d2, bp_bn, bp_p2, bp_hm, bp_paf);
    // 3. d2 = relu(conv3x3(pd1; 32->64)) @192  [MFMA 4x48, 2 exact rounds]
    d2_mfma4_kernel<<<8 * 48 * 4, BS, 0, stream>>>(
        pd1sp_h, pd1sp_l, bp_d2, b_d2, d2sp_h, d2sp_l, pd2sp_h, pd2sp_l);
    // 5. bn = relu(conv3x3(pd2; 64->128)) @96  [MFMA split-in; split-only out]
    conv3x3s_mfma_kernel<2, 8, 96, 96, 1><<<8 * 48 * 3, BS, 0, stream>>>(
        pd2sp_h, pd2sp_l, bp_bn, b_bn, bnsp_h, bnsp_l);
    // 6. u1 = relu(conv3x3(concat(up2(bn), d2); 192->64)) @192  [MFMA 4x48]
    u1_mfma_kernel<<<8 * 48 * 4, BS, 0, stream>>>(
        bnsp_h, bnsp_l, d2sp_h, d2sp_l, bp_u1, b_u1, u1sp_h, u1sp_l);
    // 7. d1' = relu(conv3x3(x; 3->32)) @384  (recompute, split-only out)
    {
        dim3 g(nblk((long)N * H * (W / 8)), 32 / 8);
        conv3x3_x8_kernel<1, 8, 1><<<g, BS, 0, stream>>>(
            x, 3, nullptr, 0, w_d1, b_d1, nullptr, N, H, W, 32, 1, d1sp_h, d1sp_l);
    }
    // 8. seg via fused MFMA u2+seg @384  [MFMA 8x48]
    u2seg_mfma_kernel<<<8 * 48 * 8, BSW, 0, stream>>>(
        u1sp_h, u1sp_l, d1sp_h, d1sp_l, bp_u2, b_u2, w_seg, b_seg, out_seg);
    // 9. p1 = relu(conv3x3_s2(concat(x, seg); 4->64)) @384->192  [vector TCO16]
    {
        dim3 g(nblk((long)N * H2 * (W2 / 4)), 64 / 16);
        conv3x3_s2_co_kernel<16, 1><<<g, BS, 0, stream>>>(
            x, 3, out_seg, 1, w_p1, b_p1, nullptr, N, H, W, 64, 1, p1sp_h, p1sp_l);
    }
    // 10. p2 = relu(conv3x3_s2(p1; 64->128)) @192->96  [MFMA s2, 3 blk/CU]
    conv3x3s2s_mfma_kernel<2, 8, 192><<<8 * 48 * 3, BS, 0, stream>>>(
        p1sp_h, p1sp_l, bp_p2, b_p2, p2sp_h, p2sp_l);
    // 11+12. hm + paf merged: conv1x1 heads @96  [MFMA, one staging pass]
    conv1x1_heads_kernel<<<8 * 144, BS, 0, stream>>>(
        p2sp_h, p2sp_l, bp_hm, bp_paf, b_hm, b_paf, out_hm, out_paf, H4 * W4);
    // 13. peaks @96  (overwrites packed-weight region - already consumed)
    peaks_kernel<<<nblk((long)N * 17 * H4 * W4), BS, 0, stream>>>(
        out_hm, out_peaks, N * 17, H4, W4, 0.1f);
}